// Round 12
// baseline (309.592 us; speedup 1.0000x reference)
//
#include <hip/hip_runtime.h>
#include <math.h>

// ---------------------------------------------------------------------------
// mLSTM cell, MFMA bf16. Round 12: cross-tile software pipeline inside the
// block — iteration t runs QK(t) and PV(t-1) back-to-back (independent MFMA
// chains), W double-buffered in LDS, V double-buffered in registers (coalesced
// frag-stream), K gload_lds double-buffered. ONE barrier per tile (end), with
// vmcnt(0)+lgkm(0) draining ops issued a full body earlier. Numerics identical
// to rounds 3-11 (absmax 0.0390625).
// ---------------------------------------------------------------------------

#define BB   2
#define SS   2048
#define DD   1024
#define NHH  4
#define DHH  256
#define BHH  (BB*NHH)

// Workspace byte offsets (total ~32.5 MB)
#define QB_OFF   ((size_t)0)
#define KB_OFF   ((size_t)8  << 20)
#define VF_OFF   ((size_t)16 << 20)   // V fragment stream, 8 MB
#define VB_OFF   ((size_t)24 << 20)
#define IG_OFF   ((size_t)32 << 20)
#define LSF_OFF  (IG_OFF  + ((size_t)64<<10))
#define AA_OFF   (LSF_OFF + ((size_t)64<<10))
#define MM_OFF   (AA_OFF  + ((size_t)64<<10))
#define FLR_OFF  (MM_OFF  + ((size_t)64<<10))
#define WSI_OFF  (FLR_OFF + ((size_t)64<<10))
#define WSF_OFF  (WSI_OFF + ((size_t)32<<10))

typedef __attribute__((ext_vector_type(8))) short short8;   // 8 bf16 (4 VGPR)
typedef __attribute__((ext_vector_type(4))) float f32x4;

typedef const __attribute__((address_space(1))) unsigned int* gas1_u32;
typedef __attribute__((address_space(3))) unsigned int* las3_u32;

__device__ __forceinline__ unsigned short f2b(float f) {
  union { float f; unsigned int u; } v; v.f = f;
  unsigned int r = (v.u + 0x7FFFu + ((v.u >> 16) & 1u)) >> 16;
  return (unsigned short)r;
}

__device__ __forceinline__ void gload_lds16(void* lds, const void* g) {
  __builtin_amdgcn_global_load_lds((gas1_u32)g, (las3_u32)lds, 16, 0, 0);
}

__device__ __forceinline__ float dot4(float4 a, float4 b) {
  return a.x*b.x + a.y*b.y + a.z*b.z + a.w*b.w;
}

// ---------------------------------------------------------------------------
// Kernel 0: gate weight pre-sum: wsum[n][c] = sum of 3 D-segments.
// ---------------------------------------------------------------------------
__global__ __launch_bounds__(256) void k_gw(
    const float* __restrict__ wi, const float* __restrict__ wf,
    float* __restrict__ wsi, float* __restrict__ wsf)
{
  const int idx = blockIdx.x*256 + threadIdx.x;   // 0..8191
  const int n = idx >> 10, c = idx & 1023;
  wsi[idx] = wi[n*3*DD + c] + wi[n*3*DD + DD + c] + wi[n*3*DD + 2*DD + c];
  wsf[idx] = wf[n*3*DD + c] + wf[n*3*DD + DD + c] + wf[n*3*DD + 2*DD + c];
}

// ---------------------------------------------------------------------------
// Kernel 1: headwise QKV projection + gate GEMVs, 4 rows/block.
// ---------------------------------------------------------------------------
__global__ __launch_bounds__(256) void k_proj(
    const float* __restrict__ x,
    const float* __restrict__ wq, const float* __restrict__ wk, const float* __restrict__ wv,
    const float* __restrict__ wsi, const float* __restrict__ bi,
    const float* __restrict__ wsf, const float* __restrict__ bf,
    unsigned short* __restrict__ qb, unsigned short* __restrict__ kb,
    unsigned short* __restrict__ vb, float* __restrict__ ig, float* __restrict__ lsf)
{
  const int rb = blockIdx.x;           // 0..1023, 4 rows each
  const int g  = threadIdx.x;          // qkv head 0..255
  const int h   = g >> 6;
  const int dh0 = (g & 63) << 2;
  const int c   = g << 2;
  const int lane = g & 63, wid = g >> 6;

  const float4 q0 = *(const float4*)(wq + g*16 + 0);
  const float4 q1 = *(const float4*)(wq + g*16 + 4);
  const float4 q2 = *(const float4*)(wq + g*16 + 8);
  const float4 q3 = *(const float4*)(wq + g*16 + 12);
  const float4 k0 = *(const float4*)(wk + g*16 + 0);
  const float4 k1 = *(const float4*)(wk + g*16 + 4);
  const float4 k2 = *(const float4*)(wk + g*16 + 8);
  const float4 k3 = *(const float4*)(wk + g*16 + 12);
  const float4 v0 = *(const float4*)(wv + g*16 + 0);
  const float4 v1 = *(const float4*)(wv + g*16 + 4);
  const float4 v2 = *(const float4*)(wv + g*16 + 8);
  const float4 v3 = *(const float4*)(wv + g*16 + 12);
  const float4 gi0 = *(const float4*)(wsi + 0*DD + c);
  const float4 gi1 = *(const float4*)(wsi + 1*DD + c);
  const float4 gi2 = *(const float4*)(wsi + 2*DD + c);
  const float4 gi3 = *(const float4*)(wsi + 3*DD + c);
  const float4 gf0 = *(const float4*)(wsf + 0*DD + c);
  const float4 gf1 = *(const float4*)(wsf + 1*DD + c);
  const float4 gf2 = *(const float4*)(wsf + 2*DD + c);
  const float4 gf3 = *(const float4*)(wsf + 3*DD + c);

  __shared__ float redI[4][4][4];   // [row][n][wid]
  __shared__ float redF[4][4][4];

  #pragma unroll
  for (int r4 = 0; r4 < 4; ++r4) {
    const int row = rb*4 + r4;
    const int b = row >> 11, s = row & (SS-1);
    const float4 xv = *(const float4*)(x + (size_t)row*DD + c);
    const size_t qi = ((size_t)(b*NHH + h)*SS + s)*DHH + dh0;

    ushort4 r;
    r.x = f2b(dot4(q0,xv)); r.y = f2b(dot4(q1,xv));
    r.z = f2b(dot4(q2,xv)); r.w = f2b(dot4(q3,xv));
    *(ushort4*)(qb + qi) = r;
    r.x = f2b(0.0625f*dot4(k0,xv)); r.y = f2b(0.0625f*dot4(k1,xv));
    r.z = f2b(0.0625f*dot4(k2,xv)); r.w = f2b(0.0625f*dot4(k3,xv));
    *(ushort4*)(kb + qi) = r;
    r.x = f2b(dot4(v0,xv)); r.y = f2b(dot4(v1,xv));
    r.z = f2b(dot4(v2,xv)); r.w = f2b(dot4(v3,xv));
    *(ushort4*)(vb + qi) = r;

    float pi0 = dot4(gi0,xv), pi1 = dot4(gi1,xv), pi2 = dot4(gi2,xv), pi3 = dot4(gi3,xv);
    float pf0 = dot4(gf0,xv), pf1 = dot4(gf1,xv), pf2 = dot4(gf2,xv), pf3 = dot4(gf3,xv);
    #pragma unroll
    for (int off=32; off>0; off>>=1) {
      pi0 += __shfl_down(pi0, off); pi1 += __shfl_down(pi1, off);
      pi2 += __shfl_down(pi2, off); pi3 += __shfl_down(pi3, off);
      pf0 += __shfl_down(pf0, off); pf1 += __shfl_down(pf1, off);
      pf2 += __shfl_down(pf2, off); pf3 += __shfl_down(pf3, off);
    }
    if (lane == 0) {
      redI[r4][0][wid] = pi0; redI[r4][1][wid] = pi1;
      redI[r4][2][wid] = pi2; redI[r4][3][wid] = pi3;
      redF[r4][0][wid] = pf0; redF[r4][1][wid] = pf1;
      redF[r4][2][wid] = pf2; redF[r4][3][wid] = pf3;
    }
  }
  __syncthreads();
  if (g < 16) {
    const int r4 = g >> 2, n = g & 3;
    const int row = rb*4 + r4;
    const int b = row >> 11, s = row & (SS-1);
    float ti = redI[r4][n][0]+redI[r4][n][1]+redI[r4][n][2]+redI[r4][n][3] + bi[n];
    float tf = redF[r4][n][0]+redF[r4][n][1]+redF[r4][n][2]+redF[r4][n][3] + bf[n];
    ig[(size_t)(b*NHH+n)*SS + s] = ti;
    float ls = (tf >= 0.f) ? -log1pf(expf(-tf)) : (tf - log1pf(expf(tf)));
    lsf[(size_t)(b*NHH+n)*SS + s] = ls;
  }
}

// ---------------------------------------------------------------------------
// Kernel 2: per-(b,head) scan.
// ---------------------------------------------------------------------------
__global__ __launch_bounds__(256) void k_scan(
    const float* __restrict__ ig, const float* __restrict__ lsf,
    float* __restrict__ aa, float* __restrict__ mm, float* __restrict__ flr)
{
  const int bh = blockIdx.x;
  const int tid = threadIdx.x;
  const float* igp = ig + (size_t)bh*SS;
  const float* lsp = lsf + (size_t)bh*SS;
  float* ap = aa + (size_t)bh*SS;
  float* mp = mm + (size_t)bh*SS;
  float* fp = flr + (size_t)bh*SS;

  __shared__ float sb[256];
  const int base = tid*8;
  float l[8], c[8];
  #pragma unroll
  for (int j=0;j<8;j++) l[j] = lsp[base+j];
  c[0] = l[0];
  #pragma unroll
  for (int j=1;j<8;j++) c[j] = c[j-1] + l[j];

  sb[tid] = c[7];
  __syncthreads();
  for (int off=1; off<256; off<<=1) {
    float v = sb[tid];
    float u = (tid>=off) ? sb[tid-off] : 0.f;
    __syncthreads();
    sb[tid] = v + u;
    __syncthreads();
  }
  const float exs = (tid==0) ? 0.f : sb[tid-1];

  float cs[8], a8[8], mx[8];
  #pragma unroll
  for (int j=0;j<8;j++) { cs[j] = exs + c[j]; a8[j] = igp[base+j] - cs[j]; }
  mx[0] = a8[0];
  #pragma unroll
  for (int j=1;j<8;j++) mx[j] = fmaxf(mx[j-1], a8[j]);

  __syncthreads();
  sb[tid] = mx[7];
  __syncthreads();
  for (int off=1; off<256; off<<=1) {
    float v = sb[tid];
    float u = (tid>=off) ? sb[tid-off] : -INFINITY;
    __syncthreads();
    sb[tid] = fmaxf(v, u);
    __syncthreads();
  }
  const float exm = (tid==0) ? -INFINITY : sb[tid-1];

  #pragma unroll
  for (int j=0;j<8;j++) {
    float mmx = fmaxf(exm, mx[j]);
    ap[base+j] = a8[j];
    mp[base+j] = mmx;
    fp[base+j] = expf(-(cs[j] + mmx));
  }
}

// ---------------------------------------------------------------------------
// Kernel 3: V fragment-stream pack. VB [bh][s][d] -> VF[bh][kt][o16][8 u16]
// where o16 = ((wc*8 + (kst*4+nt))*64 + lane), content:
//   VF[...][lane][j] = V[t0 + 32*kst + 8*lg + j][64*wc + 16*nt + l15]
// ---------------------------------------------------------------------------
__global__ __launch_bounds__(256) void k_vf(
    const unsigned short* __restrict__ vb, unsigned short* __restrict__ vfo)
{
  __shared__ unsigned short tile[64][264];   // 64 t-rows x 256 d (+8 pad)
  const int bh = blockIdx.x, kt = blockIdx.y;
  const int t0 = kt*64;
  const int tid = threadIdx.x;

  #pragma unroll
  for (int i=0;i<8;i++){
    int f = tid + i*256;                 // 0..2047 16B-chunks
    int r = f >> 5, c = (f & 31)*8;
    *(uint4*)&tile[r][c] = *(const uint4*)(vb + ((size_t)bh*SS + t0 + r)*DHH + c);
  }
  __syncthreads();

  unsigned short* dst = vfo + (size_t)(bh*32 + kt)*16384;
  #pragma unroll
  for (int i=0;i<8;i++){
    int o = tid + i*256;                 // 0..2047 output 16B-chunks
    int lane = o & 63, g = o >> 6;
    int wc = g >> 3, fi = g & 7;
    int kst = fi >> 2, nt = fi & 3;
    int l15 = lane & 15, lg = (lane >> 4) & 3;
    unsigned short tmp[8];
    #pragma unroll
    for (int j=0;j<8;j++)
      tmp[j] = tile[32*kst + 8*lg + j][64*wc + 16*nt + l15];
    *(uint4*)(dst + (size_t)o*8) = *(uint4*)tmp;
  }
}

// ---------------------------------------------------------------------------
// Kernel 4: MFMA attention, cross-tile pipelined, ONE barrier per tile.
// 256 blocks = 8 bh (XCD pin) x 32 pairs; bands [32p,32p+32) and
// [2016-32p,2048-32p) share one k-sweep of nktB tiles (act-gated).
// Iteration t: stage K(t+1) | issue V(t)->regs (coalesced frag stream) |
// QK(t) from K-slot t&1 | PV(t-1) from W-slot (t-1)&1 + V regs (ping-pong) |
// W(t) -> W-slot t&1 | [vmcnt(0)+lgkm(0); barrier].
// LDS: K dbuf 2x32KB + W dbuf 2x8KB + red 3KB = 84992 B.
// ---------------------------------------------------------------------------
__global__ __launch_bounds__(512, 1) void k_attn(
    const unsigned short* __restrict__ qb, const unsigned short* __restrict__ kb,
    const unsigned short* __restrict__ vfr,
    const float* __restrict__ ab, const float* __restrict__ mb,
    const float* __restrict__ flr, const float* __restrict__ ln_w,
    float* __restrict__ out)
{
  extern __shared__ char sm[];
  char* smK = sm;                          // 2 x 32768
  char* smW = sm + 65536;                  // 2 x 8192 (64 rows x 128B, swizzled)
  float* smRed = (float*)(sm + 81920);     // 64 x 4
  float* smS1  = smRed + 256;              // 64 x 4
  float* smS2  = smS1 + 256;               // 64 x 4

  const int bid = blockIdx.x;
  const int bh  = bid & 7;                 // XCD pin
  const int p   = bid >> 3;                // pair 0..31
  const int s0A = 32*p;
  const int s0B = 2016 - 32*p;
  const int nktA = (32*p + 95) >> 6;
  const int nktB = (2111 - 32*p) >> 6;     // 17..32 (p=0 deepest, runs first)

  const int tid  = threadIdx.x;
  const int lane = tid & 63;
  const int wid  = tid >> 6;
  const int wr   = wid >> 2;               // 0 = band A, 1 = band B
  const int wc   = wid & 3;                // col strip / d slice
  const int l15  = lane & 15, lg = lane >> 4;
  const int bhoff = bh * SS;
  const int b = bh >> 2, h = bh & 3;

  const int s0w  = wr ? s0B : s0A;
  const int nktW = wr ? nktB : nktA;

  const char* kbh = (const char*)(kb + (size_t)bh*SS*DHH);   // rows of 512B
  const unsigned short* vfh = vfr + (size_t)bh*32*16384;     // frag stream
  const int trel = 16*wc + l15;            // QKT col within k-tile, 0..63

  // ---- prologue: stage K(0) into slot 0, Q frags, m ----
  {
    #pragma unroll
    for (int i=0;i<4;i++) {
      int f = tid + i*512;
      int r = f >> 5, ch = f & 31;
      gload_lds16(smK + (size_t)f*16, kbh + (size_t)r*512 + ((ch ^ (r & 7))<<4));
    }
  }

  short8 qf[2][8];
  {
    const unsigned short* qp = qb + ((size_t)bh*SS + s0w)*DHH;
    #pragma unroll
    for (int mt=0; mt<2; ++mt)
      #pragma unroll
      for (int ks=0; ks<8; ++ks)
        qf[mt][ks] = *(const short8*)(qp + (16*mt + l15)*DHH + 32*ks + 8*lg);
  }
  float mrow[2][4];
  #pragma unroll
  for (int mt=0; mt<2; ++mt)
    #pragma unroll
    for (int rr=0; rr<4; ++rr)
      mrow[mt][rr] = mb[bhoff + s0w + 16*mt + 4*lg + rr];

  f32x4 oacc[2][4];
  #pragma unroll
  for (int mt=0; mt<2; ++mt)
    #pragma unroll
    for (int nt=0; nt<4; ++nt)
      oacc[mt][nt] = (f32x4){0.f,0.f,0.f,0.f};
  float denp[2][4] = {{0.f,0.f,0.f,0.f},{0.f,0.f,0.f,0.f}};

  short8 vA0, vA1, vA2, vA3, vA4, vA5, vA6, vA7;
  short8 vB0, vB1, vB2, vB3, vB4, vB5, vB6, vB7;
  bool pvact = false;

  asm volatile("s_waitcnt vmcnt(0) lgkmcnt(0)" ::: "memory");
  __builtin_amdgcn_s_barrier();
  asm volatile("" ::: "memory");

#define PV_MFMA(V0,V1,V2,V3,V4,V5,V6,V7, WB)                                   \
  do {                                                                         \
    const int sr0 = 32*wr + l15;                                               \
    const int sr1 = 32*wr + 16 + l15;                                          \
    short8 w00 = *(const short8*)((WB) + (size_t)sr0*128 + ((lg^(sr0&7))<<4)); \
    short8 w10 = *(const short8*)((WB) + (size_t)sr1*128 + ((lg^(sr1&7))<<4)); \
    short8 w01 = *(const short8*)((WB) + (size_t)sr0*128 + (((4+lg)^(sr0&7))<<4)); \
    short8 w11 = *(const short8*)((WB) + (size_t)sr1*128 + (((4+lg)^(sr1&7))<<4)); \
    __builtin_amdgcn_s_setprio(1);                                             \
    oacc[0][0] = __builtin_amdgcn_mfma_f32_16x16x32_bf16(w00, V0, oacc[0][0], 0,0,0); \
    oacc[1][0] = __builtin_amdgcn_mfma_f32_16x16x32_bf16(w10, V0, oacc[1][0], 0,0,0); \
    oacc[0][1] = __builtin_amdgcn_mfma_f32_16x16x32_bf16(w00, V1, oacc[0][1], 0,0,0); \
    oacc[1][1] = __builtin_amdgcn_mfma_f32_16x16x32_bf16(w10, V1, oacc[1][1], 0,0,0); \
    oacc[0][2] = __builtin_amdgcn_mfma_f32_16x16x32_bf16(w00, V2, oacc[0][2], 0,0,0); \
    oacc[1][2] = __builtin_amdgcn_mfma_f32_16x16x32_bf16(w10, V2, oacc[1][2], 0,0,0); \
    oacc[0][3] = __builtin_amdgcn_mfma_f32_16x16x32_bf16(w00, V3, oacc[0][3], 0,0,0); \
    oacc[1][3] = __builtin_amdgcn_mfma_f32_16x16x32_bf16(w10, V3, oacc[1][3], 0,0,0); \
    oacc[0][0] = __builtin_amdgcn_mfma_f32_16x16x32_bf16(w01, V4, oacc[0][0], 0,0,0); \
    oacc[1][0] = __builtin_amdgcn_mfma_f32_16x16x32_bf16(w11, V4, oacc[1][0], 0,0,0); \
    oacc[0][1] = __builtin_amdgcn_mfma_f32_16x16x32_bf16(w01, V5, oacc[0][1], 0,0,0); \
    oacc[1][1] = __builtin_amdgcn_mfma_f32_16x16x32_bf16(w11, V5, oacc[1][1], 0,0,0); \
    oacc[0][2] = __builtin_amdgcn_mfma_f32_16x16x32_bf16(w01, V6, oacc[0][2], 0,0,0); \
    oacc[1][2] = __builtin_amdgcn_mfma_f32_16x16x32_bf16(w11, V6, oacc[1][2], 0,0,0); \
    oacc[0][3] = __builtin_amdgcn_mfma_f32_16x16x32_bf16(w01, V7, oacc[0][3], 0,0,0); \
    oacc[1][3] = __builtin_amdgcn_mfma_f32_16x16x32_bf16(w11, V7, oacc[1][3], 0,0,0); \
    __builtin_amdgcn_s_setprio(0);                                             \
  } while(0)

#define TILE_BODY(VP0,VP1,VP2,VP3,VP4,VP5,VP6,VP7,                             \
                  VC0,VC1,VC2,VC3,VC4,VC5,VC6,VC7)                             \
  do {                                                                         \
    const int t0 = kt*64;                                                      \
    const bool act = (kt < nktW);                                              \
    /* 1. stage K(kt+1) (clamped) into slot (kt+1)&1 */                        \
    {                                                                          \
      const int tn = (kt+1 < nktB) ? (kt+1) : kt;                              \
      const char* kg = kbh + (size_t)tn*64*512;                                \
      char* klw = smK + ((kt+1)&1)*32768;                                      \
      _Pragma("unroll")                                                        \
      for (int i=0;i<4;i++) {                                                  \
        int f = tid + i*512;                                                   \
        int r = f >> 5, ch = f & 31;                                           \
        gload_lds16(klw + (size_t)f*16, kg + (size_t)r*512 + ((ch ^ (r & 7))<<4)); \
      }                                                                        \
    }                                                                          \
    /* 2. issue V(kt) frag stream + a[t] */                                    \
    float avC = 0.f;                                                           \
    if (act) {                                                                 \
      const unsigned short* vfp = vfh + (size_t)kt*16384 + (size_t)wc*4096 + lane*8; \
      VC0 = *(const short8*)(vfp + 0*512);                                     \
      VC1 = *(const short8*)(vfp + 1*512);                                     \
      VC2 = *(const short8*)(vfp + 2*512);                                     \
      VC3 = *(const short8*)(vfp + 3*512);                                     \
      VC4 = *(const short8*)(vfp + 4*512);                                     \
      VC5 = *(const short8*)(vfp + 5*512);                                     \
      VC6 = *(const short8*)(vfp + 6*512);                                     \
      VC7 = *(const short8*)(vfp + 7*512);                                     \
      avC = ab[bhoff + t0 + trel];                                             \
    }                                                                          \
    asm volatile("" ::: "memory");   /* pin V issues before QK */              \
    /* 3. QK(kt) from K slot kt&1 */                                           \
    f32x4 sacc0 = (f32x4){0.f,0.f,0.f,0.f};                                    \
    f32x4 sacc1 = (f32x4){0.f,0.f,0.f,0.f};                                    \
    if (act) {                                                                 \
      const char* kl = smK + (kt&1)*32768;                                     \
      __builtin_amdgcn_s_setprio(1);                                           \
      _Pragma("unroll")                                                        \
      for (int ks=0; ks<8; ++ks) {                                             \
        short8 kf = *(const short8*)(kl + (size_t)trel*512 + (((4*ks + lg) ^ (trel & 7))<<4)); \
        sacc0 = __builtin_amdgcn_mfma_f32_16x16x32_bf16(qf[0][ks], kf, sacc0, 0,0,0); \
        sacc1 = __builtin_amdgcn_mfma_f32_16x16x32_bf16(qf[1][ks], kf, sacc1, 0,0,0); \
      }                                                                        \
      __builtin_amdgcn_s_setprio(0);                                           \
    }                                                                          \
    /* 4. PV(kt-1): W slot (kt-1)&1 + V ping-pong regs */                      \
    if (pvact) {                                                               \
      const char* wb = smW + (((kt+1)&1)<<13);                                 \
      PV_MFMA(VP0,VP1,VP2,VP3,VP4,VP5,VP6,VP7, wb);                            \
    }                                                                          \
    /* 5. W(kt) -> slot kt&1 */                                                \
    if (act) {                                                                 \
      char* wb = smW + ((kt&1)<<13);                                           \
      const bool lastt = (kt == nktW-1);                                       \
      _Pragma("unroll")                                                        \
      for (int mt=0; mt<2; ++mt) {                                             \
        _Pragma("unroll")                                                      \
        for (int rr=0; rr<4; ++rr) {                                           \
          const int rib  = 16*mt + 4*lg + rr;                                  \
          const int srel = 32*wr + rib;                                        \
          float wv = (mt ? sacc1[rr] : sacc0[rr]) * __expf(avC - mrow[mt][rr]);\
          if (lastt && (t0 + trel > s0w + rib)) wv = 0.f;                      \
          denp[mt][rr] += wv;                                                  \
          *(unsigned short*)(wb + (size_t)srel*128 + (((trel >> 3) ^ (srel & 7))<<4) \
                              + ((trel & 7)<<1)) = f2b(wv);                    \
        }                                                                      \
      }                                                                        \
    }                                                                          \
    pvact = act;                                                               \
    /* 6. single end-of-tile sync: stage(kt+1)+V(kt) had a full body of cover */\
    asm volatile("s_waitcnt vmcnt(0) lgkmcnt(0)" ::: "memory");                \
    __builtin_amdgcn_s_barrier();                                              \
    asm volatile("" ::: "memory");                                             \
  } while(0)

  {
    int kt = 0;
    while (kt < nktB) {
      TILE_BODY(vA0,vA1,vA2,vA3,vA4,vA5,vA6,vA7,
                vB0,vB1,vB2,vB3,vB4,vB5,vB6,vB7);   // loads V(kt) into vB
      ++kt;
      if (kt >= nktB) break;
      TILE_BODY(vB0,vB1,vB2,vB3,vB4,vB5,vB6,vB7,
                vA0,vA1,vA2,vA3,vA4,vA5,vA6,vA7);   // loads V(kt) into vA
      ++kt;
    }
  }

  // ---- tail PV for the last tile ----
  if ((nktB-1) < nktW) {
    const char* wb = smW + (((nktB-1)&1)<<13);
    if ((nktB-1)&1) {
      PV_MFMA(vA0,vA1,vA2,vA3,vA4,vA5,vA6,vA7, wb);
    } else {
      PV_MFMA(vB0,vB1,vB2,vB3,vB4,vB5,vB6,vB7, wb);
    }
  }
#undef TILE_BODY
#undef PV_MFMA

  // ---- epilogue: den reduce, normalizer, LN, write ----
  __syncthreads();
  #pragma unroll
  for (int mt=0; mt<2; ++mt)
    #pragma unroll
    for (int rr=0; rr<4; ++rr) {
      float v = denp[mt][rr];
      v += __shfl_xor(v, 1); v += __shfl_xor(v, 2);
      v += __shfl_xor(v, 4); v += __shfl_xor(v, 8);
      if (l15 == 0) smRed[(32*wr + 16*mt + 4*lg + rr)*4 + wc] = v;
    }
  __syncthreads();

  float inv[2][4];
  #pragma unroll
  for (int mt=0; mt<2; ++mt)
    #pragma unroll
    for (int rr=0; rr<4; ++rr) {
      const int rib  = 16*mt + 4*lg + rr;
      const int srel = 32*wr + rib;
      float dsum = smRed[srel*4+0] + smRed[srel*4+1] + smRed[srel*4+2] + smRed[srel*4+3];
      float f = flr[bhoff + s0w + rib];
      inv[mt][rr] = 1.f / (fmaxf(fabsf(dsum), f) + 1e-8f);
    }

  float s1p[2][4] = {{0,0,0,0},{0,0,0,0}}, s2p[2][4] = {{0,0,0,0},{0,0,0,0}};
  #pragma unroll
  for (int mt=0; mt<2; ++mt)
    #pragma unroll
    for (int nt=0; nt<4; ++nt)
      #pragma unroll
      for (int rr=0; rr<4; ++rr) {
        float v = oacc[mt][nt][rr] * inv[mt][rr];
        oacc[mt][nt][rr] = v;
        s1p[mt][rr] += v;
        s2p[mt][rr] += v*v;
      }
  #pragma unroll
  for (int mt=0; mt<2; ++mt)
    #pragma unroll
    for (int rr=0; rr<4; ++rr) {
      float a = s1p[mt][rr], q = s2p[mt][rr];
      a += __shfl_xor(a, 1); a += __shfl_xor(a, 2);
      a += __shfl_xor(a, 4); a += __shfl_xor(a, 8);
      q += __shfl_xor(q, 1); q += __shfl_xor(q, 2);
      q += __shfl_xor(q, 4); q += __shfl_xor(q, 8);
      if (l15 == 0) {
        const int srel = 32*wr + 16*mt + 4*lg + rr;
        smS1[srel*4 + wc] = a;
        smS2[srel*4 + wc] = q;
      }
    }
  __syncthreads();

  float g4[4];
  #pragma unroll
  for (int nt=0; nt<4; ++nt) g4[nt] = 1.f + ln_w[h*DHH + 64*wc + 16*nt + l15];

  #pragma unroll
  for (int mt=0; mt<2; ++mt)
    #pragma unroll
    for (int rr=0; rr<4; ++rr) {
      const int rib  = 16*mt + 4*lg + rr;
      const int srel = 32*wr + rib;
      const float ms = smS1[srel*4+0] + smS1[srel*4+1] + smS1[srel*4+2] + smS1[srel*4+3];
      const float sq = smS2[srel*4+0] + smS2[srel*4+1] + smS2[srel*4+2] + smS2[srel*4+3];
      const float mean = ms * (1.f/DHH);
      const float var  = sq * (1.f/DHH) - mean*mean;
      const float rstd = rsqrtf(var + 1e-5f);
      float* op = out + ((size_t)(b*SS + s0w + rib))*DD + h*DHH;
      #pragma unroll
      for (int nt=0; nt<4; ++nt)
        op[64*wc + 16*nt + l15] = (oacc[mt][nt][rr] - mean)*rstd*g4[nt];
    }
}

// ---------------------------------------------------------------------------
extern "C" void kernel_launch(void* const* d_in, const int* in_sizes, int n_in,
                              void* d_out, int out_size, void* d_ws, size_t ws_size,
                              hipStream_t stream) {
  (void)in_sizes; (void)n_in; (void)out_size; (void)ws_size;
  const float* x    = (const float*)d_in[0];
  const float* wq   = (const float*)d_in[1];
  const float* wk   = (const float*)d_in[2];
  const float* wv   = (const float*)d_in[3];
  const float* wi   = (const float*)d_in[4];
  const float* bi   = (const float*)d_in[5];
  const float* wf   = (const float*)d_in[6];
  const float* bf   = (const float*)d_in[7];
  const float* ln_w = (const float*)d_in[8];
  float* out = (float*)d_out;
  char* ws = (char*)d_ws;

  unsigned short* QB = (unsigned short*)(ws + QB_OFF);
  unsigned short* KB = (unsigned short*)(ws + KB_OFF);
  unsigned short* VF = (unsigned short*)(ws + VF_OFF);
  unsigned short* VB = (unsigned short*)(ws + VB_OFF);
  float* IG  = (float*)(ws + IG_OFF);
  float* LSF = (float*)(ws + LSF_OFF);
  float* AA  = (float*)(ws + AA_OFF);
  float* MM  = (float*)(ws + MM_OFF);
  float* FLR = (float*)(ws + FLR_OFF);
  float* WSI = (float*)(ws + WSI_OFF);
  float* WSF = (float*)(ws + WSF_OFF);

  k_gw<<<32, 256, 0, stream>>>(wi, wf, WSI, WSF);
  k_proj<<<1024, 256, 0, stream>>>(x, wq, wk, wv, WSI, bi, WSF, bf, QB, KB, VB, IG, LSF);
  k_scan<<<BHH, 256, 0, stream>>>(IG, LSF, AA, MM, FLR);
  k_vf<<<dim3(BHH, SS/64), 256, 0, stream>>>(VB, VF);
  k_attn<<<256, 512, 84992, stream>>>(QB, KB, VF, AA, MM, FLR, ln_w, out);
}

// Round 13
// 107.035 us; speedup vs baseline: 2.8924x; 2.8924x over previous
//
#include <hip/hip_runtime.h>
#include <math.h>

// ---------------------------------------------------------------------------
// mLSTM cell, MFMA bf16. Round 13: TLP-first k_attn. 512 blocks x 256 thr
// (4 waves, one 32-row q-band each). K and V pre-packed into fragment-stream
// layouts (coalesced 1KB/instruction L2->reg loads, consumed in-phase; no
// register state across barriers). Only W transits LDS (4KB) -> barriers are
// lgkm-only. ~6KB LDS + ~160 VGPR -> 3 blocks/CU: blocks cover each other's
// latency (the missing ingredient of rounds 7-12). Numerics unchanged.
// ---------------------------------------------------------------------------

#define BB   2
#define SS   2048
#define DD   1024
#define NHH  4
#define DHH  256
#define BHH  (BB*NHH)

// Workspace byte offsets (~40.4 MB)
#define QB_OFF   ((size_t)0)
#define KB_OFF   ((size_t)8  << 20)
#define VF_OFF   ((size_t)16 << 20)   // V fragment stream, 8 MB
#define VB_OFF   ((size_t)24 << 20)
#define KF_OFF   ((size_t)32 << 20)   // K fragment stream, 8 MB
#define IG_OFF   ((size_t)40 << 20)
#define LSF_OFF  (IG_OFF  + ((size_t)64<<10))
#define AA_OFF   (LSF_OFF + ((size_t)64<<10))
#define MM_OFF   (AA_OFF  + ((size_t)64<<10))
#define FLR_OFF  (MM_OFF  + ((size_t)64<<10))
#define WSI_OFF  (FLR_OFF + ((size_t)64<<10))
#define WSF_OFF  (WSI_OFF + ((size_t)32<<10))

typedef __attribute__((ext_vector_type(8))) short short8;   // 8 bf16 (4 VGPR)
typedef __attribute__((ext_vector_type(4))) float f32x4;

__device__ __forceinline__ unsigned short f2b(float f) {
  union { float f; unsigned int u; } v; v.f = f;
  unsigned int r = (v.u + 0x7FFFu + ((v.u >> 16) & 1u)) >> 16;
  return (unsigned short)r;
}

__device__ __forceinline__ float dot4(float4 a, float4 b) {
  return a.x*b.x + a.y*b.y + a.z*b.z + a.w*b.w;
}

// ---------------------------------------------------------------------------
// Kernel 0: gate weight pre-sum.
// ---------------------------------------------------------------------------
__global__ __launch_bounds__(256) void k_gw(
    const float* __restrict__ wi, const float* __restrict__ wf,
    float* __restrict__ wsi, float* __restrict__ wsf)
{
  const int idx = blockIdx.x*256 + threadIdx.x;   // 0..8191
  const int n = idx >> 10, c = idx & 1023;
  wsi[idx] = wi[n*3*DD + c] + wi[n*3*DD + DD + c] + wi[n*3*DD + 2*DD + c];
  wsf[idx] = wf[n*3*DD + c] + wf[n*3*DD + DD + c] + wf[n*3*DD + 2*DD + c];
}

// ---------------------------------------------------------------------------
// Kernel 1: headwise QKV projection + gate GEMVs, 4 rows/block.
// ---------------------------------------------------------------------------
__global__ __launch_bounds__(256) void k_proj(
    const float* __restrict__ x,
    const float* __restrict__ wq, const float* __restrict__ wk, const float* __restrict__ wv,
    const float* __restrict__ wsi, const float* __restrict__ bi,
    const float* __restrict__ wsf, const float* __restrict__ bf,
    unsigned short* __restrict__ qb, unsigned short* __restrict__ kb,
    unsigned short* __restrict__ vb, float* __restrict__ ig, float* __restrict__ lsf)
{
  const int rb = blockIdx.x;           // 0..1023, 4 rows each
  const int g  = threadIdx.x;          // qkv head 0..255
  const int h   = g >> 6;
  const int dh0 = (g & 63) << 2;
  const int c   = g << 2;
  const int lane = g & 63, wid = g >> 6;

  const float4 q0 = *(const float4*)(wq + g*16 + 0);
  const float4 q1 = *(const float4*)(wq + g*16 + 4);
  const float4 q2 = *(const float4*)(wq + g*16 + 8);
  const float4 q3 = *(const float4*)(wq + g*16 + 12);
  const float4 k0 = *(const float4*)(wk + g*16 + 0);
  const float4 k1 = *(const float4*)(wk + g*16 + 4);
  const float4 k2 = *(const float4*)(wk + g*16 + 8);
  const float4 k3 = *(const float4*)(wk + g*16 + 12);
  const float4 v0 = *(const float4*)(wv + g*16 + 0);
  const float4 v1 = *(const float4*)(wv + g*16 + 4);
  const float4 v2 = *(const float4*)(wv + g*16 + 8);
  const float4 v3 = *(const float4*)(wv + g*16 + 12);
  const float4 gi0 = *(const float4*)(wsi + 0*DD + c);
  const float4 gi1 = *(const float4*)(wsi + 1*DD + c);
  const float4 gi2 = *(const float4*)(wsi + 2*DD + c);
  const float4 gi3 = *(const float4*)(wsi + 3*DD + c);
  const float4 gf0 = *(const float4*)(wsf + 0*DD + c);
  const float4 gf1 = *(const float4*)(wsf + 1*DD + c);
  const float4 gf2 = *(const float4*)(wsf + 2*DD + c);
  const float4 gf3 = *(const float4*)(wsf + 3*DD + c);

  __shared__ float redI[4][4][4];   // [row][n][wid]
  __shared__ float redF[4][4][4];

  #pragma unroll
  for (int r4 = 0; r4 < 4; ++r4) {
    const int row = rb*4 + r4;
    const int b = row >> 11, s = row & (SS-1);
    const float4 xv = *(const float4*)(x + (size_t)row*DD + c);
    const size_t qi = ((size_t)(b*NHH + h)*SS + s)*DHH + dh0;

    ushort4 r;
    r.x = f2b(dot4(q0,xv)); r.y = f2b(dot4(q1,xv));
    r.z = f2b(dot4(q2,xv)); r.w = f2b(dot4(q3,xv));
    *(ushort4*)(qb + qi) = r;
    r.x = f2b(0.0625f*dot4(k0,xv)); r.y = f2b(0.0625f*dot4(k1,xv));
    r.z = f2b(0.0625f*dot4(k2,xv)); r.w = f2b(0.0625f*dot4(k3,xv));
    *(ushort4*)(kb + qi) = r;
    r.x = f2b(dot4(v0,xv)); r.y = f2b(dot4(v1,xv));
    r.z = f2b(dot4(v2,xv)); r.w = f2b(dot4(v3,xv));
    *(ushort4*)(vb + qi) = r;

    float pi0 = dot4(gi0,xv), pi1 = dot4(gi1,xv), pi2 = dot4(gi2,xv), pi3 = dot4(gi3,xv);
    float pf0 = dot4(gf0,xv), pf1 = dot4(gf1,xv), pf2 = dot4(gf2,xv), pf3 = dot4(gf3,xv);
    #pragma unroll
    for (int off=32; off>0; off>>=1) {
      pi0 += __shfl_down(pi0, off); pi1 += __shfl_down(pi1, off);
      pi2 += __shfl_down(pi2, off); pi3 += __shfl_down(pi3, off);
      pf0 += __shfl_down(pf0, off); pf1 += __shfl_down(pf1, off);
      pf2 += __shfl_down(pf2, off); pf3 += __shfl_down(pf3, off);
    }
    if (lane == 0) {
      redI[r4][0][wid] = pi0; redI[r4][1][wid] = pi1;
      redI[r4][2][wid] = pi2; redI[r4][3][wid] = pi3;
      redF[r4][0][wid] = pf0; redF[r4][1][wid] = pf1;
      redF[r4][2][wid] = pf2; redF[r4][3][wid] = pf3;
    }
  }
  __syncthreads();
  if (g < 16) {
    const int r4 = g >> 2, n = g & 3;
    const int row = rb*4 + r4;
    const int b = row >> 11, s = row & (SS-1);
    float ti = redI[r4][n][0]+redI[r4][n][1]+redI[r4][n][2]+redI[r4][n][3] + bi[n];
    float tf = redF[r4][n][0]+redF[r4][n][1]+redF[r4][n][2]+redF[r4][n][3] + bf[n];
    ig[(size_t)(b*NHH+n)*SS + s] = ti;
    float ls = (tf >= 0.f) ? -log1pf(expf(-tf)) : (tf - log1pf(expf(tf)));
    lsf[(size_t)(b*NHH+n)*SS + s] = ls;
  }
}

// ---------------------------------------------------------------------------
// Kernel 2: per-(b,head) scan.
// ---------------------------------------------------------------------------
__global__ __launch_bounds__(256) void k_scan(
    const float* __restrict__ ig, const float* __restrict__ lsf,
    float* __restrict__ aa, float* __restrict__ mm, float* __restrict__ flr)
{
  const int bh = blockIdx.x;
  const int tid = threadIdx.x;
  const float* igp = ig + (size_t)bh*SS;
  const float* lsp = lsf + (size_t)bh*SS;
  float* ap = aa + (size_t)bh*SS;
  float* mp = mm + (size_t)bh*SS;
  float* fp = flr + (size_t)bh*SS;

  __shared__ float sb[256];
  const int base = tid*8;
  float l[8], c[8];
  #pragma unroll
  for (int j=0;j<8;j++) l[j] = lsp[base+j];
  c[0] = l[0];
  #pragma unroll
  for (int j=1;j<8;j++) c[j] = c[j-1] + l[j];

  sb[tid] = c[7];
  __syncthreads();
  for (int off=1; off<256; off<<=1) {
    float v = sb[tid];
    float u = (tid>=off) ? sb[tid-off] : 0.f;
    __syncthreads();
    sb[tid] = v + u;
    __syncthreads();
  }
  const float exs = (tid==0) ? 0.f : sb[tid-1];

  float cs[8], a8[8], mx[8];
  #pragma unroll
  for (int j=0;j<8;j++) { cs[j] = exs + c[j]; a8[j] = igp[base+j] - cs[j]; }
  mx[0] = a8[0];
  #pragma unroll
  for (int j=1;j<8;j++) mx[j] = fmaxf(mx[j-1], a8[j]);

  __syncthreads();
  sb[tid] = mx[7];
  __syncthreads();
  for (int off=1; off<256; off<<=1) {
    float v = sb[tid];
    float u = (tid>=off) ? sb[tid-off] : -INFINITY;
    __syncthreads();
    sb[tid] = fmaxf(v, u);
    __syncthreads();
  }
  const float exm = (tid==0) ? -INFINITY : sb[tid-1];

  #pragma unroll
  for (int j=0;j<8;j++) {
    float mmx = fmaxf(exm, mx[j]);
    ap[base+j] = a8[j];
    mp[base+j] = mmx;
    fp[base+j] = expf(-(cs[j] + mmx));
  }
}

// ---------------------------------------------------------------------------
// Kernel 3a: K fragment-stream pack. KB [bh][s][d] -> KF chunks
// o = (wc*8 + ks)*64 + lane ; content[j] = K[t0+16*wc+l15][32*ks+8*lg+j].
// In k_attn, kf load = base + ks*512 + lane*8 -> 64x16B contiguous stream.
// ---------------------------------------------------------------------------
__global__ __launch_bounds__(256) void k_kf(
    const unsigned short* __restrict__ kb, unsigned short* __restrict__ kfo)
{
  __shared__ unsigned short tile[64][264];
  const int bh = blockIdx.x, kt = blockIdx.y;
  const int t0 = kt*64;
  const int tid = threadIdx.x;

  #pragma unroll
  for (int i=0;i<8;i++){
    int f = tid + i*256;
    int r = f >> 5, c = (f & 31)*8;
    *(uint4*)&tile[r][c] = *(const uint4*)(kb + ((size_t)bh*SS + t0 + r)*DHH + c);
  }
  __syncthreads();

  unsigned short* dst = kfo + (size_t)(bh*32 + kt)*16384;
  #pragma unroll
  for (int i=0;i<8;i++){
    int o = tid + i*256;
    int lane = o & 63, g = o >> 6;
    int wcq = g >> 3, ks = g & 7;
    int l15 = lane & 15, lg = (lane >> 4) & 3;
    *(uint4*)(dst + (size_t)o*8) = *(const uint4*)&tile[16*wcq + l15][32*ks + 8*lg];
  }
}

// ---------------------------------------------------------------------------
// Kernel 3b: V fragment-stream pack (round-11 validated).
// o = ((wc*8 + kst*4+nt)*64 + lane); content[j] = V[t0+32*kst+8*lg+j][64*wc+16*nt+l15].
// ---------------------------------------------------------------------------
__global__ __launch_bounds__(256) void k_vf(
    const unsigned short* __restrict__ vb, unsigned short* __restrict__ vfo)
{
  __shared__ unsigned short tile[64][264];
  const int bh = blockIdx.x, kt = blockIdx.y;
  const int t0 = kt*64;
  const int tid = threadIdx.x;

  #pragma unroll
  for (int i=0;i<8;i++){
    int f = tid + i*256;
    int r = f >> 5, c = (f & 31)*8;
    *(uint4*)&tile[r][c] = *(const uint4*)(vb + ((size_t)bh*SS + t0 + r)*DHH + c);
  }
  __syncthreads();

  unsigned short* dst = vfo + (size_t)(bh*32 + kt)*16384;
  #pragma unroll
  for (int i=0;i<8;i++){
    int o = tid + i*256;
    int lane = o & 63, g = o >> 6;
    int wc = g >> 3, fi = g & 7;
    int kst = fi >> 2, nt = fi & 3;
    int l15 = lane & 15, lg = (lane >> 4) & 3;
    unsigned short tmp[8];
    #pragma unroll
    for (int j=0;j<8;j++)
      tmp[j] = tile[32*kst + 8*lg + j][64*wc + 16*nt + l15];
    *(uint4*)(dst + (size_t)o*8) = *(uint4*)tmp;
  }
}

// ---------------------------------------------------------------------------
// Kernel 4: MFMA attention, TLP-first. 512 blocks x 256 threads (4 waves).
// Block (bh = bid&7 XCD pin, i = bid>>3): rt = i<32 ? 63-i : i-32 (deepest
// first; co-resident pairs (i,i+32) sum to ~33 tiles -> balanced CU work).
// Per tile: kf stream -> QK -> W(LDS, swizzled) -> [lgkm0; barrier] ->
// vf stream + W reads -> PV -> [lgkm0; barrier]. No gload_lds, no vmem at
// barriers; K/V consumed in-phase (no cross-barrier register state).
// LDS: W 4KB + red 1.5KB. ~3 blocks/CU cover each other's latency.
// ---------------------------------------------------------------------------
__global__ __launch_bounds__(256, 3) void k_attn(
    const unsigned short* __restrict__ qb, const unsigned short* __restrict__ kfr,
    const unsigned short* __restrict__ vfr,
    const float* __restrict__ ab, const float* __restrict__ mb,
    const float* __restrict__ flr, const float* __restrict__ ln_w,
    float* __restrict__ out)
{
  __shared__ __align__(16) char smW[32*128];   // 32 rows x 128B, swizzled
  __shared__ float smRed[32*4];
  __shared__ float smS1[32*4];
  __shared__ float smS2[32*4];

  const int bid = blockIdx.x;
  const int bh  = bid & 7;                 // XCD pin
  const int i   = bid >> 3;                // 0..63
  const int rt  = (i < 32) ? (63 - i) : (i - 32);
  const int s0  = rt * 32;
  const int nkt = (32*rt + 95) >> 6;       // 1..32

  const int tid  = threadIdx.x;
  const int lane = tid & 63;
  const int wc   = tid >> 6;               // wave 0..3 (col strip / d slice)
  const int l15  = lane & 15, lg = lane >> 4;
  const int bhoff = bh * SS;
  const int b = bh >> 2, h = bh & 3;
  const int trel = 16*wc + l15;

  const unsigned short* kfh = kfr + (size_t)bh*32*16384;
  const unsigned short* vfh = vfr + (size_t)bh*32*16384;

  // Q register-resident: 32 rows (two 16-row sub-bands mt)
  short8 qf[2][8];
  {
    const unsigned short* qp = qb + ((size_t)bh*SS + s0)*DHH;
    #pragma unroll
    for (int mt=0; mt<2; ++mt)
      #pragma unroll
      for (int ks=0; ks<8; ++ks)
        qf[mt][ks] = *(const short8*)(qp + (16*mt + l15)*DHH + 32*ks + 8*lg);
  }
  float mrow[2][4];
  #pragma unroll
  for (int mt=0; mt<2; ++mt)
    #pragma unroll
    for (int rr=0; rr<4; ++rr)
      mrow[mt][rr] = mb[bhoff + s0 + 16*mt + 4*lg + rr];

  f32x4 oacc[2][4];
  #pragma unroll
  for (int mt=0; mt<2; ++mt)
    #pragma unroll
    for (int nt=0; nt<4; ++nt)
      oacc[mt][nt] = (f32x4){0.f,0.f,0.f,0.f};
  float denp[2][4] = {{0.f,0.f,0.f,0.f},{0.f,0.f,0.f,0.f}};

  for (int kt = 0; kt < nkt; ++kt) {
    const int t0 = kt*64;

    // ---- QK: K fragment stream (8 x 1KB coalesced loads), MFMA ----
    f32x4 sacc0 = (f32x4){0.f,0.f,0.f,0.f};
    f32x4 sacc1 = (f32x4){0.f,0.f,0.f,0.f};
    const float avC = ab[bhoff + t0 + trel];
    {
      const unsigned short* kfp = kfh + (size_t)kt*16384 + (size_t)wc*4096 + lane*8;
      short8 k0 = *(const short8*)(kfp + 0*512);
      short8 k1 = *(const short8*)(kfp + 1*512);
      short8 k2 = *(const short8*)(kfp + 2*512);
      short8 k3 = *(const short8*)(kfp + 3*512);
      short8 k4 = *(const short8*)(kfp + 4*512);
      short8 k5 = *(const short8*)(kfp + 5*512);
      short8 k6 = *(const short8*)(kfp + 6*512);
      short8 k7 = *(const short8*)(kfp + 7*512);
      __builtin_amdgcn_s_setprio(1);
      sacc0 = __builtin_amdgcn_mfma_f32_16x16x32_bf16(qf[0][0], k0, sacc0, 0,0,0);
      sacc1 = __builtin_amdgcn_mfma_f32_16x16x32_bf16(qf[1][0], k0, sacc1, 0,0,0);
      sacc0 = __builtin_amdgcn_mfma_f32_16x16x32_bf16(qf[0][1], k1, sacc0, 0,0,0);
      sacc1 = __builtin_amdgcn_mfma_f32_16x16x32_bf16(qf[1][1], k1, sacc1, 0,0,0);
      sacc0 = __builtin_amdgcn_mfma_f32_16x16x32_bf16(qf[0][2], k2, sacc0, 0,0,0);
      sacc1 = __builtin_amdgcn_mfma_f32_16x16x32_bf16(qf[1][2], k2, sacc1, 0,0,0);
      sacc0 = __builtin_amdgcn_mfma_f32_16x16x32_bf16(qf[0][3], k3, sacc0, 0,0,0);
      sacc1 = __builtin_amdgcn_mfma_f32_16x16x32_bf16(qf[1][3], k3, sacc1, 0,0,0);
      sacc0 = __builtin_amdgcn_mfma_f32_16x16x32_bf16(qf[0][4], k4, sacc0, 0,0,0);
      sacc1 = __builtin_amdgcn_mfma_f32_16x16x32_bf16(qf[1][4], k4, sacc1, 0,0,0);
      sacc0 = __builtin_amdgcn_mfma_f32_16x16x32_bf16(qf[0][5], k5, sacc0, 0,0,0);
      sacc1 = __builtin_amdgcn_mfma_f32_16x16x32_bf16(qf[1][5], k5, sacc1, 0,0,0);
      sacc0 = __builtin_amdgcn_mfma_f32_16x16x32_bf16(qf[0][6], k6, sacc0, 0,0,0);
      sacc1 = __builtin_amdgcn_mfma_f32_16x16x32_bf16(qf[1][6], k6, sacc1, 0,0,0);
      sacc0 = __builtin_amdgcn_mfma_f32_16x16x32_bf16(qf[0][7], k7, sacc0, 0,0,0);
      sacc1 = __builtin_amdgcn_mfma_f32_16x16x32_bf16(qf[1][7], k7, sacc1, 0,0,0);
      __builtin_amdgcn_s_setprio(0);
    }

    // ---- W = mask * qk * exp(a[t]-m[s]) -> bf16 swizzled LDS ----
    {
      const bool lastt = (kt == nkt-1);
      #pragma unroll
      for (int mt=0; mt<2; ++mt) {
        #pragma unroll
        for (int rr=0; rr<4; ++rr) {
          const int rib = 16*mt + 4*lg + rr;
          float wv = (mt ? sacc1[rr] : sacc0[rr]) * __expf(avC - mrow[mt][rr]);
          if (lastt && (t0 + trel > s0 + rib)) wv = 0.f;
          denp[mt][rr] += wv;
          *(unsigned short*)(smW + (size_t)rib*128 + (((trel >> 3) ^ (rib & 7))<<4)
                              + ((trel & 7)<<1)) = f2b(wv);
        }
      }
    }
    asm volatile("s_waitcnt lgkmcnt(0)" ::: "memory");
    __builtin_amdgcn_s_barrier();
    asm volatile("" ::: "memory");

    // ---- PV: V fragment stream + W from LDS ----
    {
      const unsigned short* vfp = vfh + (size_t)kt*16384 + (size_t)wc*4096 + lane*8;
      short8 v0 = *(const short8*)(vfp + 0*512);
      short8 v1 = *(const short8*)(vfp + 1*512);
      short8 v2 = *(const short8*)(vfp + 2*512);
      short8 v3 = *(const short8*)(vfp + 3*512);
      short8 v4 = *(const short8*)(vfp + 4*512);
      short8 v5 = *(const short8*)(vfp + 5*512);
      short8 v6 = *(const short8*)(vfp + 6*512);
      short8 v7 = *(const short8*)(vfp + 7*512);
      const int sr0 = l15, sr1 = 16 + l15;
      short8 w00 = *(const short8*)(smW + (size_t)sr0*128 + ((lg^(sr0&7))<<4));
      short8 w10 = *(const short8*)(smW + (size_t)sr1*128 + ((lg^(sr1&7))<<4));
      short8 w01 = *(const short8*)(smW + (size_t)sr0*128 + (((4+lg)^(sr0&7))<<4));
      short8 w11 = *(const short8*)(smW + (size_t)sr1*128 + (((4+lg)^(sr1&7))<<4));
      __builtin_amdgcn_s_setprio(1);
      oacc[0][0] = __builtin_amdgcn_mfma_f32_16x16x32_bf16(w00, v0, oacc[0][0], 0,0,0);
      oacc[1][0] = __builtin_amdgcn_mfma_f32_16x16x32_bf16(w10, v0, oacc[1][0], 0,0,0);
      oacc[0][1] = __builtin_amdgcn_mfma_f32_16x16x32_bf16(w00, v1, oacc[0][1], 0,0,0);
      oacc[1][1] = __builtin_amdgcn_mfma_f32_16x16x32_bf16(w10, v1, oacc[1][1], 0,0,0);
      oacc[0][2] = __builtin_amdgcn_mfma_f32_16x16x32_bf16(w00, v2, oacc[0][2], 0,0,0);
      oacc[1][2] = __builtin_amdgcn_mfma_f32_16x16x32_bf16(w10, v2, oacc[1][2], 0,0,0);
      oacc[0][3] = __builtin_amdgcn_mfma_f32_16x16x32_bf16(w00, v3, oacc[0][3], 0,0,0);
      oacc[1][3] = __builtin_amdgcn_mfma_f32_16x16x32_bf16(w10, v3, oacc[1][3], 0,0,0);
      oacc[0][0] = __builtin_amdgcn_mfma_f32_16x16x32_bf16(w01, v4, oacc[0][0], 0,0,0);
      oacc[1][0] = __builtin_amdgcn_mfma_f32_16x16x32_bf16(w11, v4, oacc[1][0], 0,0,0);
      oacc[0][1] = __builtin_amdgcn_mfma_f32_16x16x32_bf16(w01, v5, oacc[0][1], 0,0,0);
      oacc[1][1] = __builtin_amdgcn_mfma_f32_16x16x32_bf16(w11, v5, oacc[1][1], 0,0,0);
      oacc[0][2] = __builtin_amdgcn_mfma_f32_16x16x32_bf16(w01, v6, oacc[0][2], 0,0,0);
      oacc[1][2] = __builtin_amdgcn_mfma_f32_16x16x32_bf16(w11, v6, oacc[1][2], 0,0,0);
      oacc[0][3] = __builtin_amdgcn_mfma_f32_16x16x32_bf16(w01, v7, oacc[0][3], 0,0,0);
      oacc[1][3] = __builtin_amdgcn_mfma_f32_16x16x32_bf16(w11, v7, oacc[1][3], 0,0,0);
      __builtin_amdgcn_s_setprio(0);
    }
    asm volatile("s_waitcnt lgkmcnt(0)" ::: "memory");
    __builtin_amdgcn_s_barrier();
    asm volatile("" ::: "memory");
  }

  // ---- epilogue: den reduce, normalizer, LN, write ----
  #pragma unroll
  for (int mt=0; mt<2; ++mt)
    #pragma unroll
    for (int rr=0; rr<4; ++rr) {
      float v = denp[mt][rr];
      v += __shfl_xor(v, 1); v += __shfl_xor(v, 2);
      v += __shfl_xor(v, 4); v += __shfl_xor(v, 8);
      if (l15 == 0) smRed[(16*mt + 4*lg + rr)*4 + wc] = v;
    }
  __syncthreads();

  float inv[2][4];
  #pragma unroll
  for (int mt=0; mt<2; ++mt)
    #pragma unroll
    for (int rr=0; rr<4; ++rr) {
      const int rib = 16*mt + 4*lg + rr;
      float dsum = smRed[rib*4+0] + smRed[rib*4+1] + smRed[rib*4+2] + smRed[rib*4+3];
      float f = flr[bhoff + s0 + rib];
      inv[mt][rr] = 1.f / (fmaxf(fabsf(dsum), f) + 1e-8f);
    }

  float s1p[2][4] = {{0,0,0,0},{0,0,0,0}}, s2p[2][4] = {{0,0,0,0},{0,0,0,0}};
  #pragma unroll
  for (int mt=0; mt<2; ++mt)
    #pragma unroll
    for (int nt=0; nt<4; ++nt)
      #pragma unroll
      for (int rr=0; rr<4; ++rr) {
        float v = oacc[mt][nt][rr] * inv[mt][rr];
        oacc[mt][nt][rr] = v;
        s1p[mt][rr] += v;
        s2p[mt][rr] += v*v;
      }
  #pragma unroll
  for (int mt=0; mt<2; ++mt)
    #pragma unroll
    for (int rr=0; rr<4; ++rr) {
      float a = s1p[mt][rr], q = s2p[mt][rr];
      a += __shfl_xor(a, 1); a += __shfl_xor(a, 2);
      a += __shfl_xor(a, 4); a += __shfl_xor(a, 8);
      q += __shfl_xor(q, 1); q += __shfl_xor(q, 2);
      q += __shfl_xor(q, 4); q += __shfl_xor(q, 8);
      if (l15 == 0) {
        const int rib = 16*mt + 4*lg + rr;
        smS1[rib*4 + wc] = a;
        smS2[rib*4 + wc] = q;
      }
    }
  __syncthreads();

  float g4[4];
  #pragma unroll
  for (int nt=0; nt<4; ++nt) g4[nt] = 1.f + ln_w[h*DHH + 64*wc + 16*nt + l15];

  #pragma unroll
  for (int mt=0; mt<2; ++mt)
    #pragma unroll
    for (int rr=0; rr<4; ++rr) {
      const int rib = 16*mt + 4*lg + rr;
      const float ms = smS1[rib*4+0] + smS1[rib*4+1] + smS1[rib*4+2] + smS1[rib*4+3];
      const float sq = smS2[rib*4+0] + smS2[rib*4+1] + smS2[rib*4+2] + smS2[rib*4+3];
      const float mean = ms * (1.f/DHH);
      const float var  = sq * (1.f/DHH) - mean*mean;
      const float rstd = rsqrtf(var + 1e-5f);
      float* op = out + ((size_t)(b*SS + s0 + rib))*DD + h*DHH;
      #pragma unroll
      for (int nt=0; nt<4; ++nt)
        op[64*wc + 16*nt + l15] = (oacc[mt][nt][rr] - mean)*rstd*g4[nt];
    }
}

// ---------------------------------------------------------------------------
extern "C" void kernel_launch(void* const* d_in, const int* in_sizes, int n_in,
                              void* d_out, int out_size, void* d_ws, size_t ws_size,
                              hipStream_t stream) {
  (void)in_sizes; (void)n_in; (void)out_size; (void)ws_size;
  const float* x    = (const float*)d_in[0];
  const float* wq   = (const float*)d_in[1];
  const float* wk   = (const float*)d_in[2];
  const float* wv   = (const float*)d_in[3];
  const float* wi   = (const float*)d_in[4];
  const float* bi   = (const float*)d_in[5];
  const float* wf   = (const float*)d_in[6];
  const float* bf   = (const float*)d_in[7];
  const float* ln_w = (const float*)d_in[8];
  float* out = (float*)d_out;
  char* ws = (char*)d_ws;

  unsigned short* QB = (unsigned short*)(ws + QB_OFF);
  unsigned short* KB = (unsigned short*)(ws + KB_OFF);
  unsigned short* VF = (unsigned short*)(ws + VF_OFF);
  unsigned short* VB = (unsigned short*)(ws + VB_OFF);
  unsigned short* KF = (unsigned short*)(ws + KF_OFF);
  float* IG  = (float*)(ws + IG_OFF);
  float* LSF = (float*)(ws + LSF_OFF);
  float* AA  = (float*)(ws + AA_OFF);
  float* MM  = (float*)(ws + MM_OFF);
  float* FLR = (float*)(ws + FLR_OFF);
  float* WSI = (float*)(ws + WSI_OFF);
  float* WSF = (float*)(ws + WSF_OFF);

  k_gw<<<32, 256, 0, stream>>>(wi, wf, WSI, WSF);
  k_proj<<<1024, 256, 0, stream>>>(x, wq, wk, wv, WSI, bi, WSF, bf, QB, KB, VB, IG, LSF);
  k_scan<<<BHH, 256, 0, stream>>>(IG, LSF, AA, MM, FLR);
  k_kf<<<dim3(BHH, SS/64), 256, 0, stream>>>(KB, KF);
  k_vf<<<dim3(BHH, SS/64), 256, 0, stream>>>(VB, VF);
  k_attn<<<512, 256, 0, stream>>>(QB, KF, VF, AA, MM, FLR, ln_w, out);
}

// Round 14
// 90.010 us; speedup vs baseline: 3.4395x; 1.1892x over previous
//
#include <hip/hip_runtime.h>
#include <math.h>

// ---------------------------------------------------------------------------
// mLSTM cell, MFMA bf16. Round 14: 512 blocks x 256 thr (4 waves), 2/CU.
// K via gload_lds double-buffer (counted waits: stage(kt+1) drains at next
// tile's top vmcnt(0) -> full-body cover). V via coalesced frag-stream L2->reg
// issued at tile TOP (before K-stage; sched_barrier pins order), pinned before
// the mid barrier -> compiler waits vmcnt(8), K-stage stays in flight.
// One barrier pair per tile. W via 4KB swizzled LDS. Numerics unchanged.
// ---------------------------------------------------------------------------

#define BB   2
#define SS   2048
#define DD   1024
#define NHH  4
#define DHH  256
#define BHH  (BB*NHH)

// Workspace byte offsets (~32.5 MB)
#define QB_OFF   ((size_t)0)
#define KB_OFF   ((size_t)8  << 20)
#define VF_OFF   ((size_t)16 << 20)   // V fragment stream, 8 MB
#define VB_OFF   ((size_t)24 << 20)
#define IG_OFF   ((size_t)32 << 20)
#define LSF_OFF  (IG_OFF  + ((size_t)64<<10))
#define AA_OFF   (LSF_OFF + ((size_t)64<<10))
#define MM_OFF   (AA_OFF  + ((size_t)64<<10))
#define FLR_OFF  (MM_OFF  + ((size_t)64<<10))
#define WSI_OFF  (FLR_OFF + ((size_t)64<<10))
#define WSF_OFF  (WSI_OFF + ((size_t)32<<10))

typedef __attribute__((ext_vector_type(8))) short short8;   // 8 bf16 (4 VGPR)
typedef __attribute__((ext_vector_type(4))) float f32x4;

typedef const __attribute__((address_space(1))) unsigned int* gas1_u32;
typedef __attribute__((address_space(3))) unsigned int* las3_u32;

__device__ __forceinline__ unsigned short f2b(float f) {
  union { float f; unsigned int u; } v; v.f = f;
  unsigned int r = (v.u + 0x7FFFu + ((v.u >> 16) & 1u)) >> 16;
  return (unsigned short)r;
}

__device__ __forceinline__ void gload_lds16(void* lds, const void* g) {
  __builtin_amdgcn_global_load_lds((gas1_u32)g, (las3_u32)lds, 16, 0, 0);
}

__device__ __forceinline__ float dot4(float4 a, float4 b) {
  return a.x*b.x + a.y*b.y + a.z*b.z + a.w*b.w;
}

// ---------------------------------------------------------------------------
// Kernel 0: gate weight pre-sum.
// ---------------------------------------------------------------------------
__global__ __launch_bounds__(256) void k_gw(
    const float* __restrict__ wi, const float* __restrict__ wf,
    float* __restrict__ wsi, float* __restrict__ wsf)
{
  const int idx = blockIdx.x*256 + threadIdx.x;   // 0..8191
  const int n = idx >> 10, c = idx & 1023;
  wsi[idx] = wi[n*3*DD + c] + wi[n*3*DD + DD + c] + wi[n*3*DD + 2*DD + c];
  wsf[idx] = wf[n*3*DD + c] + wf[n*3*DD + DD + c] + wf[n*3*DD + 2*DD + c];
}

// ---------------------------------------------------------------------------
// Kernel 1: headwise QKV projection + gate GEMVs, 4 rows/block.
// ---------------------------------------------------------------------------
__global__ __launch_bounds__(256) void k_proj(
    const float* __restrict__ x,
    const float* __restrict__ wq, const float* __restrict__ wk, const float* __restrict__ wv,
    const float* __restrict__ wsi, const float* __restrict__ bi,
    const float* __restrict__ wsf, const float* __restrict__ bf,
    unsigned short* __restrict__ qb, unsigned short* __restrict__ kb,
    unsigned short* __restrict__ vb, float* __restrict__ ig, float* __restrict__ lsf)
{
  const int rb = blockIdx.x;           // 0..1023, 4 rows each
  const int g  = threadIdx.x;          // qkv head 0..255
  const int h   = g >> 6;
  const int dh0 = (g & 63) << 2;
  const int c   = g << 2;
  const int lane = g & 63, wid = g >> 6;

  const float4 q0 = *(const float4*)(wq + g*16 + 0);
  const float4 q1 = *(const float4*)(wq + g*16 + 4);
  const float4 q2 = *(const float4*)(wq + g*16 + 8);
  const float4 q3 = *(const float4*)(wq + g*16 + 12);
  const float4 k0 = *(const float4*)(wk + g*16 + 0);
  const float4 k1 = *(const float4*)(wk + g*16 + 4);
  const float4 k2 = *(const float4*)(wk + g*16 + 8);
  const float4 k3 = *(const float4*)(wk + g*16 + 12);
  const float4 v0 = *(const float4*)(wv + g*16 + 0);
  const float4 v1 = *(const float4*)(wv + g*16 + 4);
  const float4 v2 = *(const float4*)(wv + g*16 + 8);
  const float4 v3 = *(const float4*)(wv + g*16 + 12);
  const float4 gi0 = *(const float4*)(wsi + 0*DD + c);
  const float4 gi1 = *(const float4*)(wsi + 1*DD + c);
  const float4 gi2 = *(const float4*)(wsi + 2*DD + c);
  const float4 gi3 = *(const float4*)(wsi + 3*DD + c);
  const float4 gf0 = *(const float4*)(wsf + 0*DD + c);
  const float4 gf1 = *(const float4*)(wsf + 1*DD + c);
  const float4 gf2 = *(const float4*)(wsf + 2*DD + c);
  const float4 gf3 = *(const float4*)(wsf + 3*DD + c);

  __shared__ float redI[4][4][4];   // [row][n][wid]
  __shared__ float redF[4][4][4];

  #pragma unroll
  for (int r4 = 0; r4 < 4; ++r4) {
    const int row = rb*4 + r4;
    const int b = row >> 11, s = row & (SS-1);
    const float4 xv = *(const float4*)(x + (size_t)row*DD + c);
    const size_t qi = ((size_t)(b*NHH + h)*SS + s)*DHH + dh0;

    ushort4 r;
    r.x = f2b(dot4(q0,xv)); r.y = f2b(dot4(q1,xv));
    r.z = f2b(dot4(q2,xv)); r.w = f2b(dot4(q3,xv));
    *(ushort4*)(qb + qi) = r;
    r.x = f2b(0.0625f*dot4(k0,xv)); r.y = f2b(0.0625f*dot4(k1,xv));
    r.z = f2b(0.0625f*dot4(k2,xv)); r.w = f2b(0.0625f*dot4(k3,xv));
    *(ushort4*)(kb + qi) = r;
    r.x = f2b(dot4(v0,xv)); r.y = f2b(dot4(v1,xv));
    r.z = f2b(dot4(v2,xv)); r.w = f2b(dot4(v3,xv));
    *(ushort4*)(vb + qi) = r;

    float pi0 = dot4(gi0,xv), pi1 = dot4(gi1,xv), pi2 = dot4(gi2,xv), pi3 = dot4(gi3,xv);
    float pf0 = dot4(gf0,xv), pf1 = dot4(gf1,xv), pf2 = dot4(gf2,xv), pf3 = dot4(gf3,xv);
    #pragma unroll
    for (int off=32; off>0; off>>=1) {
      pi0 += __shfl_down(pi0, off); pi1 += __shfl_down(pi1, off);
      pi2 += __shfl_down(pi2, off); pi3 += __shfl_down(pi3, off);
      pf0 += __shfl_down(pf0, off); pf1 += __shfl_down(pf1, off);
      pf2 += __shfl_down(pf2, off); pf3 += __shfl_down(pf3, off);
    }
    if (lane == 0) {
      redI[r4][0][wid] = pi0; redI[r4][1][wid] = pi1;
      redI[r4][2][wid] = pi2; redI[r4][3][wid] = pi3;
      redF[r4][0][wid] = pf0; redF[r4][1][wid] = pf1;
      redF[r4][2][wid] = pf2; redF[r4][3][wid] = pf3;
    }
  }
  __syncthreads();
  if (g < 16) {
    const int r4 = g >> 2, n = g & 3;
    const int row = rb*4 + r4;
    const int b = row >> 11, s = row & (SS-1);
    float ti = redI[r4][n][0]+redI[r4][n][1]+redI[r4][n][2]+redI[r4][n][3] + bi[n];
    float tf = redF[r4][n][0]+redF[r4][n][1]+redF[r4][n][2]+redF[r4][n][3] + bf[n];
    ig[(size_t)(b*NHH+n)*SS + s] = ti;
    float ls = (tf >= 0.f) ? -log1pf(expf(-tf)) : (tf - log1pf(expf(tf)));
    lsf[(size_t)(b*NHH+n)*SS + s] = ls;
  }
}

// ---------------------------------------------------------------------------
// Kernel 2: per-(b,head) scan.
// ---------------------------------------------------------------------------
__global__ __launch_bounds__(256) void k_scan(
    const float* __restrict__ ig, const float* __restrict__ lsf,
    float* __restrict__ aa, float* __restrict__ mm, float* __restrict__ flr)
{
  const int bh = blockIdx.x;
  const int tid = threadIdx.x;
  const float* igp = ig + (size_t)bh*SS;
  const float* lsp = lsf + (size_t)bh*SS;
  float* ap = aa + (size_t)bh*SS;
  float* mp = mm + (size_t)bh*SS;
  float* fp = flr + (size_t)bh*SS;

  __shared__ float sb[256];
  const int base = tid*8;
  float l[8], c[8];
  #pragma unroll
  for (int j=0;j<8;j++) l[j] = lsp[base+j];
  c[0] = l[0];
  #pragma unroll
  for (int j=1;j<8;j++) c[j] = c[j-1] + l[j];

  sb[tid] = c[7];
  __syncthreads();
  for (int off=1; off<256; off<<=1) {
    float v = sb[tid];
    float u = (tid>=off) ? sb[tid-off] : 0.f;
    __syncthreads();
    sb[tid] = v + u;
    __syncthreads();
  }
  const float exs = (tid==0) ? 0.f : sb[tid-1];

  float cs[8], a8[8], mx[8];
  #pragma unroll
  for (int j=0;j<8;j++) { cs[j] = exs + c[j]; a8[j] = igp[base+j] - cs[j]; }
  mx[0] = a8[0];
  #pragma unroll
  for (int j=1;j<8;j++) mx[j] = fmaxf(mx[j-1], a8[j]);

  __syncthreads();
  sb[tid] = mx[7];
  __syncthreads();
  for (int off=1; off<256; off<<=1) {
    float v = sb[tid];
    float u = (tid>=off) ? sb[tid-off] : -INFINITY;
    __syncthreads();
    sb[tid] = fmaxf(v, u);
    __syncthreads();
  }
  const float exm = (tid==0) ? -INFINITY : sb[tid-1];

  #pragma unroll
  for (int j=0;j<8;j++) {
    float mmx = fmaxf(exm, mx[j]);
    ap[base+j] = a8[j];
    mp[base+j] = mmx;
    fp[base+j] = expf(-(cs[j] + mmx));
  }
}

// ---------------------------------------------------------------------------
// Kernel 3: V fragment-stream pack (round-11 validated).
// o = ((wc*8 + kst*4+nt)*64 + lane); content[j] = V[t0+32*kst+8*lg+j][64*wc+16*nt+l15].
// ---------------------------------------------------------------------------
__global__ __launch_bounds__(256) void k_vf(
    const unsigned short* __restrict__ vb, unsigned short* __restrict__ vfo)
{
  __shared__ unsigned short tile[64][264];
  const int bh = blockIdx.x, kt = blockIdx.y;
  const int t0 = kt*64;
  const int tid = threadIdx.x;

  #pragma unroll
  for (int i=0;i<8;i++){
    int f = tid + i*256;
    int r = f >> 5, c = (f & 31)*8;
    *(uint4*)&tile[r][c] = *(const uint4*)(vb + ((size_t)bh*SS + t0 + r)*DHH + c);
  }
  __syncthreads();

  unsigned short* dst = vfo + (size_t)(bh*32 + kt)*16384;
  #pragma unroll
  for (int i=0;i<8;i++){
    int o = tid + i*256;
    int lane = o & 63, g = o >> 6;
    int wc = g >> 3, fi = g & 7;
    int kst = fi >> 2, nt = fi & 3;
    int l15 = lane & 15, lg = (lane >> 4) & 3;
    unsigned short tmp[8];
    #pragma unroll
    for (int j=0;j<8;j++)
      tmp[j] = tile[32*kst + 8*lg + j][64*wc + 16*nt + l15];
    *(uint4*)(dst + (size_t)o*8) = *(uint4*)tmp;
  }
}

// ---------------------------------------------------------------------------
// Kernel 4: MFMA attention. 512 blocks x 256 thr (4 waves), 2 blocks/CU.
// rt = i<32 ? 63-i : i-32 (balanced CU totals, deepest dispatched first).
// Per tile: [vmcnt(0)+lgkm(0); barrier] -> issue V(kt)+av (frag stream),
// sched_barrier, issue K-stage(kt+1) (gload_lds, other buf) -> QK from
// smK[kt&1] -> W->LDS -> pin V (vmcnt(8): K-stage stays in flight) ->
// [lgkm(0); barrier] -> PV (W from LDS, V from regs).
// LDS: K dbuf 2x32KB + W 4KB + red 1.5KB = ~71KB -> 2 blocks/CU.
// ---------------------------------------------------------------------------
__global__ __launch_bounds__(256, 1) void k_attn(
    const unsigned short* __restrict__ qb, const unsigned short* __restrict__ kb,
    const unsigned short* __restrict__ vfr,
    const float* __restrict__ ab, const float* __restrict__ mb,
    const float* __restrict__ flr, const float* __restrict__ ln_w,
    float* __restrict__ out)
{
  __shared__ __align__(16) char smK[2*32768];
  __shared__ __align__(16) char smW[32*128];
  __shared__ float smRed[32*4];
  __shared__ float smS1[32*4];
  __shared__ float smS2[32*4];

  const int bid = blockIdx.x;
  const int bh  = bid & 7;                 // XCD pin
  const int i   = bid >> 3;                // 0..63
  const int rt  = (i < 32) ? (63 - i) : (i - 32);
  const int s0  = rt * 32;
  const int nkt = (32*rt + 95) >> 6;       // 1..32

  const int tid  = threadIdx.x;
  const int lane = tid & 63;
  const int wc   = tid >> 6;               // wave 0..3
  const int l15  = lane & 15, lg = lane >> 4;
  const int bhoff = bh * SS;
  const int b = bh >> 2, h = bh & 3;
  const int trel = 16*wc + l15;

  const char* kbh = (const char*)(kb + (size_t)bh*SS*DHH);   // rows of 512B
  const unsigned short* vfh = vfr + (size_t)bh*32*16384;

  // ---- prologue: stage K(0) into buf 0 ----
  #pragma unroll
  for (int ii=0; ii<8; ++ii) {
    int f = tid + ii*256;
    int r = f >> 5, ch = f & 31;
    gload_lds16(smK + (size_t)f*16, kbh + (size_t)r*512 + ((ch ^ (r & 7))<<4));
  }

  short8 qf[2][8];
  {
    const unsigned short* qp = qb + ((size_t)bh*SS + s0)*DHH;
    #pragma unroll
    for (int mt=0; mt<2; ++mt)
      #pragma unroll
      for (int ks=0; ks<8; ++ks)
        qf[mt][ks] = *(const short8*)(qp + (16*mt + l15)*DHH + 32*ks + 8*lg);
  }
  float mrow[2][4];
  #pragma unroll
  for (int mt=0; mt<2; ++mt)
    #pragma unroll
    for (int rr=0; rr<4; ++rr)
      mrow[mt][rr] = mb[bhoff + s0 + 16*mt + 4*lg + rr];

  f32x4 oacc[2][4];
  #pragma unroll
  for (int mt=0; mt<2; ++mt)
    #pragma unroll
    for (int nt=0; nt<4; ++nt)
      oacc[mt][nt] = (f32x4){0.f,0.f,0.f,0.f};
  float denp[2][4] = {{0.f,0.f,0.f,0.f},{0.f,0.f,0.f,0.f}};

  for (int kt = 0; kt < nkt; ++kt) {
    const int t0 = kt*64;

    // ---- 1. top sync: K(kt) staged (issued a full body ago), prev PV LDS
    //         reads retired (W single-buffer safe) ----
    asm volatile("s_waitcnt vmcnt(0) lgkmcnt(0)" ::: "memory");
    __builtin_amdgcn_s_barrier();
    asm volatile("" ::: "memory");

    // ---- 2. issue V(kt) frag stream + av FIRST (older than K-stage) ----
    const unsigned short* vfp = vfh + (size_t)kt*16384 + (size_t)wc*4096 + lane*8;
    short8 v0 = *(const short8*)(vfp + 0*512);
    short8 v1 = *(const short8*)(vfp + 1*512);
    short8 v2 = *(const short8*)(vfp + 2*512);
    short8 v3 = *(const short8*)(vfp + 3*512);
    short8 v4 = *(const short8*)(vfp + 4*512);
    short8 v5 = *(const short8*)(vfp + 5*512);
    short8 v6 = *(const short8*)(vfp + 6*512);
    short8 v7 = *(const short8*)(vfp + 7*512);
    const float avC = ab[bhoff + t0 + trel];
    __builtin_amdgcn_sched_barrier(0);   // pin V issue before K-stage

    // ---- 3. issue K-stage(kt+1) (clamped) into other buffer ----
    {
      const int tn = (kt+1 < nkt) ? (kt+1) : kt;
      const char* kg = kbh + (size_t)tn*64*512;
      char* klw = smK + ((kt+1)&1)*32768;
      #pragma unroll
      for (int ii=0; ii<8; ++ii) {
        int f = tid + ii*256;
        int r = f >> 5, ch = f & 31;
        gload_lds16(klw + (size_t)f*16, kg + (size_t)r*512 + ((ch ^ (r & 7))<<4));
      }
    }

    // ---- 4. QK from smK[kt&1] ----
    f32x4 sacc0 = (f32x4){0.f,0.f,0.f,0.f};
    f32x4 sacc1 = (f32x4){0.f,0.f,0.f,0.f};
    {
      const char* kl = smK + (kt&1)*32768;
      __builtin_amdgcn_s_setprio(1);
      #pragma unroll
      for (int ks=0; ks<8; ++ks) {
        short8 kf = *(const short8*)(kl + (size_t)trel*512 + (((4*ks + lg) ^ (trel & 7))<<4));
        sacc0 = __builtin_amdgcn_mfma_f32_16x16x32_bf16(qf[0][ks], kf, sacc0, 0,0,0);
        sacc1 = __builtin_amdgcn_mfma_f32_16x16x32_bf16(qf[1][ks], kf, sacc1, 0,0,0);
      }
      __builtin_amdgcn_s_setprio(0);
    }

    // ---- 5. W = mask * qk * exp(a[t]-m[s]) -> bf16 swizzled LDS ----
    {
      const bool lastt = (kt == nkt-1);
      #pragma unroll
      for (int mt=0; mt<2; ++mt) {
        #pragma unroll
        for (int rr=0; rr<4; ++rr) {
          const int rib = 16*mt + 4*lg + rr;
          float wv = (mt ? sacc1[rr] : sacc0[rr]) * __expf(avC - mrow[mt][rr]);
          if (lastt && (t0 + trel > s0 + rib)) wv = 0.f;
          denp[mt][rr] += wv;
          *(unsigned short*)(smW + (size_t)rib*128 + (((trel >> 3) ^ (rib & 7))<<4)
                              + ((trel & 7)<<1)) = f2b(wv);
        }
      }
    }

    // ---- 6. pin V in regs (forces vmcnt(8): V done, K-stage in flight) ----
    asm volatile("" :: "v"((int)v0[0]), "v"((int)v1[0]), "v"((int)v2[0]),
                       "v"((int)v3[0]), "v"((int)v4[0]), "v"((int)v5[0]),
                       "v"((int)v6[0]), "v"((int)v7[0]));
    asm volatile("s_waitcnt lgkmcnt(0)" ::: "memory");
    __builtin_amdgcn_s_barrier();
    asm volatile("" ::: "memory");

    // ---- 7. PV: W from LDS + V from registers ----
    {
      const int sr0 = l15, sr1 = 16 + l15;
      short8 w00 = *(const short8*)(smW + (size_t)sr0*128 + ((lg^(sr0&7))<<4));
      short8 w10 = *(const short8*)(smW + (size_t)sr1*128 + ((lg^(sr1&7))<<4));
      short8 w01 = *(const short8*)(smW + (size_t)sr0*128 + (((4+lg)^(sr0&7))<<4));
      short8 w11 = *(const short8*)(smW + (size_t)sr1*128 + (((4+lg)^(sr1&7))<<4));
      __builtin_amdgcn_s_setprio(1);
      oacc[0][0] = __builtin_amdgcn_mfma_f32_16x16x32_bf16(w00, v0, oacc[0][0], 0,0,0);
      oacc[1][0] = __builtin_amdgcn_mfma_f32_16x16x32_bf16(w10, v0, oacc[1][0], 0,0,0);
      oacc[0][1] = __builtin_amdgcn_mfma_f32_16x16x32_bf16(w00, v1, oacc[0][1], 0,0,0);
      oacc[1][1] = __builtin_amdgcn_mfma_f32_16x16x32_bf16(w10, v1, oacc[1][1], 0,0,0);
      oacc[0][2] = __builtin_amdgcn_mfma_f32_16x16x32_bf16(w00, v2, oacc[0][2], 0,0,0);
      oacc[1][2] = __builtin_amdgcn_mfma_f32_16x16x32_bf16(w10, v2, oacc[1][2], 0,0,0);
      oacc[0][3] = __builtin_amdgcn_mfma_f32_16x16x32_bf16(w00, v3, oacc[0][3], 0,0,0);
      oacc[1][3] = __builtin_amdgcn_mfma_f32_16x16x32_bf16(w10, v3, oacc[1][3], 0,0,0);
      oacc[0][0] = __builtin_amdgcn_mfma_f32_16x16x32_bf16(w01, v4, oacc[0][0], 0,0,0);
      oacc[1][0] = __builtin_amdgcn_mfma_f32_16x16x32_bf16(w11, v4, oacc[1][0], 0,0,0);
      oacc[0][1] = __builtin_amdgcn_mfma_f32_16x16x32_bf16(w01, v5, oacc[0][1], 0,0,0);
      oacc[1][1] = __builtin_amdgcn_mfma_f32_16x16x32_bf16(w11, v5, oacc[1][1], 0,0,0);
      oacc[0][2] = __builtin_amdgcn_mfma_f32_16x16x32_bf16(w01, v6, oacc[0][2], 0,0,0);
      oacc[1][2] = __builtin_amdgcn_mfma_f32_16x16x32_bf16(w11, v6, oacc[1][2], 0,0,0);
      oacc[0][3] = __builtin_amdgcn_mfma_f32_16x16x32_bf16(w01, v7, oacc[0][3], 0,0,0);
      oacc[1][3] = __builtin_amdgcn_mfma_f32_16x16x32_bf16(w11, v7, oacc[1][3], 0,0,0);
      __builtin_amdgcn_s_setprio(0);
    }
  }

  // ---- epilogue: den reduce, normalizer, LN, write ----
  __syncthreads();
  #pragma unroll
  for (int mt=0; mt<2; ++mt)
    #pragma unroll
    for (int rr=0; rr<4; ++rr) {
      float v = denp[mt][rr];
      v += __shfl_xor(v, 1); v += __shfl_xor(v, 2);
      v += __shfl_xor(v, 4); v += __shfl_xor(v, 8);
      if (l15 == 0) smRed[(16*mt + 4*lg + rr)*4 + wc] = v;
    }
  __syncthreads();

  float inv[2][4];
  #pragma unroll
  for (int mt=0; mt<2; ++mt)
    #pragma unroll
    for (int rr=0; rr<4; ++rr) {
      const int rib = 16*mt + 4*lg + rr;
      float dsum = smRed[rib*4+0] + smRed[rib*4+1] + smRed[rib*4+2] + smRed[rib*4+3];
      float f = flr[bhoff + s0 + rib];
      inv[mt][rr] = 1.f / (fmaxf(fabsf(dsum), f) + 1e-8f);
    }

  float s1p[2][4] = {{0,0,0,0},{0,0,0,0}}, s2p[2][4] = {{0,0,0,0},{0,0,0,0}};
  #pragma unroll
  for (int mt=0; mt<2; ++mt)
    #pragma unroll
    for (int nt=0; nt<4; ++nt)
      #pragma unroll
      for (int rr=0; rr<4; ++rr) {
        float v = oacc[mt][nt][rr] * inv[mt][rr];
        oacc[mt][nt][rr] = v;
        s1p[mt][rr] += v;
        s2p[mt][rr] += v*v;
      }
  #pragma unroll
  for (int mt=0; mt<2; ++mt)
    #pragma unroll
    for (int rr=0; rr<4; ++rr) {
      float a = s1p[mt][rr], q = s2p[mt][rr];
      a += __shfl_xor(a, 1); a += __shfl_xor(a, 2);
      a += __shfl_xor(a, 4); a += __shfl_xor(a, 8);
      q += __shfl_xor(q, 1); q += __shfl_xor(q, 2);
      q += __shfl_xor(q, 4); q += __shfl_xor(q, 8);
      if (l15 == 0) {
        const int rib = 16*mt + 4*lg + rr;
        smS1[rib*4 + wc] = a;
        smS2[rib*4 + wc] = q;
      }
    }
  __syncthreads();

  float g4[4];
  #pragma unroll
  for (int nt=0; nt<4; ++nt) g4[nt] = 1.f + ln_w[h*DHH + 64*wc + 16*nt + l15];

  #pragma unroll
  for (int mt=0; mt<2; ++mt)
    #pragma unroll
    for (int rr=0; rr<4; ++rr) {
      const int rib = 16*mt + 4*lg + rr;
      const float ms = smS1[rib*4+0] + smS1[rib*4+1] + smS1[rib*4+2] + smS1[rib*4+3];
      const float sq = smS2[rib*4+0] + smS2[rib*4+1] + smS2[rib*4+2] + smS2[rib*4+3];
      const float mean = ms * (1.f/DHH);
      const float var  = sq * (1.f/DHH) - mean*mean;
      const float rstd = rsqrtf(var + 1e-5f);
      float* op = out + ((size_t)(b*SS + s0 + rib))*DD + h*DHH;
      #pragma unroll
      for (int nt=0; nt<4; ++nt)
        op[64*wc + 16*nt + l15] = (oacc[mt][nt][rr] - mean)*rstd*g4[nt];
    }
}

// ---------------------------------------------------------------------------
extern "C" void kernel_launch(void* const* d_in, const int* in_sizes, int n_in,
                              void* d_out, int out_size, void* d_ws, size_t ws_size,
                              hipStream_t stream) {
  (void)in_sizes; (void)n_in; (void)out_size; (void)ws_size;
  const float* x    = (const float*)d_in[0];
  const float* wq   = (const float*)d_in[1];
  const float* wk   = (const float*)d_in[2];
  const float* wv   = (const float*)d_in[3];
  const float* wi   = (const float*)d_in[4];
  const float* bi   = (const float*)d_in[5];
  const float* wf   = (const float*)d_in[6];
  const float* bf   = (const float*)d_in[7];
  const float* ln_w = (const float*)d_in[8];
  float* out = (float*)d_out;
  char* ws = (char*)d_ws;

  unsigned short* QB = (unsigned short*)(ws + QB_OFF);
  unsigned short* KB = (unsigned short*)(ws + KB_OFF);
  unsigned short* VF = (unsigned short*)(ws + VF_OFF);
  unsigned short* VB = (unsigned short*)(ws + VB_OFF);
  float* IG  = (float*)(ws + IG_OFF);
  float* LSF = (float*)(ws + LSF_OFF);
  float* AA  = (float*)(ws + AA_OFF);
  float* MM  = (float*)(ws + MM_OFF);
  float* FLR = (float*)(ws + FLR_OFF);
  float* WSI = (float*)(ws + WSI_OFF);
  float* WSF = (float*)(ws + WSF_OFF);

  k_gw<<<32, 256, 0, stream>>>(wi, wf, WSI, WSF);
  k_proj<<<1024, 256, 0, stream>>>(x, wq, wk, wv, WSI, bi, WSF, bf, QB, KB, VB, IG, LSF);
  k_scan<<<BHH, 256, 0, stream>>>(IG, LSF, AA, MM, FLR);
  k_vf<<<dim3(BHH, SS/64), 256, 0, stream>>>(VB, VF);
  k_attn<<<512, 256, 0, stream>>>(QB, KB, VF, AA, MM, FLR, ln_w, out);
}

// Round 15
// 88.085 us; speedup vs baseline: 3.5147x; 1.0219x over previous
//
#include <hip/hip_runtime.h>
#include <math.h>

// ---------------------------------------------------------------------------
// mLSTM cell, MFMA bf16. Round 15: concurrency-first. 1024 blocks x 256 thr
// (16-row q-bands, 4 waves). Pure frag-stream K and V (coalesced 1KB L2->reg,
// consumed in-phase), W via 2KB swizzled LDS, lgkm-only barriers. ~70 VGPR +
// ~3KB LDS -> 4 blocks/CU co-resident (grid-limited). Snake depth map: each
// CU's four depths sum ~const -> balanced totals AND sustained multi-block
// overlap. Numerics identical to rounds 3-14 (absmax 0.0390625).
// ---------------------------------------------------------------------------

#define BB   2
#define SS   2048
#define DD   1024
#define NHH  4
#define DHH  256
#define BHH  (BB*NHH)

// Workspace byte offsets (~40.4 MB)
#define QB_OFF   ((size_t)0)
#define KB_OFF   ((size_t)8  << 20)
#define VF_OFF   ((size_t)16 << 20)   // V fragment stream, 8 MB
#define VB_OFF   ((size_t)24 << 20)
#define KF_OFF   ((size_t)32 << 20)   // K fragment stream, 8 MB
#define IG_OFF   ((size_t)40 << 20)
#define LSF_OFF  (IG_OFF  + ((size_t)64<<10))
#define AA_OFF   (LSF_OFF + ((size_t)64<<10))
#define MM_OFF   (AA_OFF  + ((size_t)64<<10))
#define FLR_OFF  (MM_OFF  + ((size_t)64<<10))
#define WSI_OFF  (FLR_OFF + ((size_t)64<<10))
#define WSF_OFF  (WSI_OFF + ((size_t)32<<10))

typedef __attribute__((ext_vector_type(8))) short short8;   // 8 bf16 (4 VGPR)
typedef __attribute__((ext_vector_type(4))) float f32x4;

__device__ __forceinline__ unsigned short f2b(float f) {
  union { float f; unsigned int u; } v; v.f = f;
  unsigned int r = (v.u + 0x7FFFu + ((v.u >> 16) & 1u)) >> 16;
  return (unsigned short)r;
}

__device__ __forceinline__ float dot4(float4 a, float4 b) {
  return a.x*b.x + a.y*b.y + a.z*b.z + a.w*b.w;
}

// ---------------------------------------------------------------------------
// Kernel 0: gate weight pre-sum.
// ---------------------------------------------------------------------------
__global__ __launch_bounds__(256) void k_gw(
    const float* __restrict__ wi, const float* __restrict__ wf,
    float* __restrict__ wsi, float* __restrict__ wsf)
{
  const int idx = blockIdx.x*256 + threadIdx.x;   // 0..8191
  const int n = idx >> 10, c = idx & 1023;
  wsi[idx] = wi[n*3*DD + c] + wi[n*3*DD + DD + c] + wi[n*3*DD + 2*DD + c];
  wsf[idx] = wf[n*3*DD + c] + wf[n*3*DD + DD + c] + wf[n*3*DD + 2*DD + c];
}

// ---------------------------------------------------------------------------
// Kernel 1: headwise QKV projection + gate GEMVs, 4 rows/block.
// ---------------------------------------------------------------------------
__global__ __launch_bounds__(256) void k_proj(
    const float* __restrict__ x,
    const float* __restrict__ wq, const float* __restrict__ wk, const float* __restrict__ wv,
    const float* __restrict__ wsi, const float* __restrict__ bi,
    const float* __restrict__ wsf, const float* __restrict__ bf,
    unsigned short* __restrict__ qb, unsigned short* __restrict__ kb,
    unsigned short* __restrict__ vb, float* __restrict__ ig, float* __restrict__ lsf)
{
  const int rb = blockIdx.x;           // 0..1023, 4 rows each
  const int g  = threadIdx.x;          // qkv head 0..255
  const int h   = g >> 6;
  const int dh0 = (g & 63) << 2;
  const int c   = g << 2;
  const int lane = g & 63, wid = g >> 6;

  const float4 q0 = *(const float4*)(wq + g*16 + 0);
  const float4 q1 = *(const float4*)(wq + g*16 + 4);
  const float4 q2 = *(const float4*)(wq + g*16 + 8);
  const float4 q3 = *(const float4*)(wq + g*16 + 12);
  const float4 k0 = *(const float4*)(wk + g*16 + 0);
  const float4 k1 = *(const float4*)(wk + g*16 + 4);
  const float4 k2 = *(const float4*)(wk + g*16 + 8);
  const float4 k3 = *(const float4*)(wk + g*16 + 12);
  const float4 v0 = *(const float4*)(wv + g*16 + 0);
  const float4 v1 = *(const float4*)(wv + g*16 + 4);
  const float4 v2 = *(const float4*)(wv + g*16 + 8);
  const float4 v3 = *(const float4*)(wv + g*16 + 12);
  const float4 gi0 = *(const float4*)(wsi + 0*DD + c);
  const float4 gi1 = *(const float4*)(wsi + 1*DD + c);
  const float4 gi2 = *(const float4*)(wsi + 2*DD + c);
  const float4 gi3 = *(const float4*)(wsi + 3*DD + c);
  const float4 gf0 = *(const float4*)(wsf + 0*DD + c);
  const float4 gf1 = *(const float4*)(wsf + 1*DD + c);
  const float4 gf2 = *(const float4*)(wsf + 2*DD + c);
  const float4 gf3 = *(const float4*)(wsf + 3*DD + c);

  __shared__ float redI[4][4][4];   // [row][n][wid]
  __shared__ float redF[4][4][4];

  #pragma unroll
  for (int r4 = 0; r4 < 4; ++r4) {
    const int row = rb*4 + r4;
    const int b = row >> 11, s = row & (SS-1);
    const float4 xv = *(const float4*)(x + (size_t)row*DD + c);
    const size_t qi = ((size_t)(b*NHH + h)*SS + s)*DHH + dh0;

    ushort4 r;
    r.x = f2b(dot4(q0,xv)); r.y = f2b(dot4(q1,xv));
    r.z = f2b(dot4(q2,xv)); r.w = f2b(dot4(q3,xv));
    *(ushort4*)(qb + qi) = r;
    r.x = f2b(0.0625f*dot4(k0,xv)); r.y = f2b(0.0625f*dot4(k1,xv));
    r.z = f2b(0.0625f*dot4(k2,xv)); r.w = f2b(0.0625f*dot4(k3,xv));
    *(ushort4*)(kb + qi) = r;
    r.x = f2b(dot4(v0,xv)); r.y = f2b(dot4(v1,xv));
    r.z = f2b(dot4(v2,xv)); r.w = f2b(dot4(v3,xv));
    *(ushort4*)(vb + qi) = r;

    float pi0 = dot4(gi0,xv), pi1 = dot4(gi1,xv), pi2 = dot4(gi2,xv), pi3 = dot4(gi3,xv);
    float pf0 = dot4(gf0,xv), pf1 = dot4(gf1,xv), pf2 = dot4(gf2,xv), pf3 = dot4(gf3,xv);
    #pragma unroll
    for (int off=32; off>0; off>>=1) {
      pi0 += __shfl_down(pi0, off); pi1 += __shfl_down(pi1, off);
      pi2 += __shfl_down(pi2, off); pi3 += __shfl_down(pi3, off);
      pf0 += __shfl_down(pf0, off); pf1 += __shfl_down(pf1, off);
      pf2 += __shfl_down(pf2, off); pf3 += __shfl_down(pf3, off);
    }
    if (lane == 0) {
      redI[r4][0][wid] = pi0; redI[r4][1][wid] = pi1;
      redI[r4][2][wid] = pi2; redI[r4][3][wid] = pi3;
      redF[r4][0][wid] = pf0; redF[r4][1][wid] = pf1;
      redF[r4][2][wid] = pf2; redF[r4][3][wid] = pf3;
    }
  }
  __syncthreads();
  if (g < 16) {
    const int r4 = g >> 2, n = g & 3;
    const int row = rb*4 + r4;
    const int b = row >> 11, s = row & (SS-1);
    float ti = redI[r4][n][0]+redI[r4][n][1]+redI[r4][n][2]+redI[r4][n][3] + bi[n];
    float tf = redF[r4][n][0]+redF[r4][n][1]+redF[r4][n][2]+redF[r4][n][3] + bf[n];
    ig[(size_t)(b*NHH+n)*SS + s] = ti;
    float ls = (tf >= 0.f) ? -log1pf(expf(-tf)) : (tf - log1pf(expf(tf)));
    lsf[(size_t)(b*NHH+n)*SS + s] = ls;
  }
}

// ---------------------------------------------------------------------------
// Kernel 2: per-(b,head) scan.
// ---------------------------------------------------------------------------
__global__ __launch_bounds__(256) void k_scan(
    const float* __restrict__ ig, const float* __restrict__ lsf,
    float* __restrict__ aa, float* __restrict__ mm, float* __restrict__ flr)
{
  const int bh = blockIdx.x;
  const int tid = threadIdx.x;
  const float* igp = ig + (size_t)bh*SS;
  const float* lsp = lsf + (size_t)bh*SS;
  float* ap = aa + (size_t)bh*SS;
  float* mp = mm + (size_t)bh*SS;
  float* fp = flr + (size_t)bh*SS;

  __shared__ float sb[256];
  const int base = tid*8;
  float l[8], c[8];
  #pragma unroll
  for (int j=0;j<8;j++) l[j] = lsp[base+j];
  c[0] = l[0];
  #pragma unroll
  for (int j=1;j<8;j++) c[j] = c[j-1] + l[j];

  sb[tid] = c[7];
  __syncthreads();
  for (int off=1; off<256; off<<=1) {
    float v = sb[tid];
    float u = (tid>=off) ? sb[tid-off] : 0.f;
    __syncthreads();
    sb[tid] = v + u;
    __syncthreads();
  }
  const float exs = (tid==0) ? 0.f : sb[tid-1];

  float cs[8], a8[8], mx[8];
  #pragma unroll
  for (int j=0;j<8;j++) { cs[j] = exs + c[j]; a8[j] = igp[base+j] - cs[j]; }
  mx[0] = a8[0];
  #pragma unroll
  for (int j=1;j<8;j++) mx[j] = fmaxf(mx[j-1], a8[j]);

  __syncthreads();
  sb[tid] = mx[7];
  __syncthreads();
  for (int off=1; off<256; off<<=1) {
    float v = sb[tid];
    float u = (tid>=off) ? sb[tid-off] : -INFINITY;
    __syncthreads();
    sb[tid] = fmaxf(v, u);
    __syncthreads();
  }
  const float exm = (tid==0) ? -INFINITY : sb[tid-1];

  #pragma unroll
  for (int j=0;j<8;j++) {
    float mmx = fmaxf(exm, mx[j]);
    ap[base+j] = a8[j];
    mp[base+j] = mmx;
    fp[base+j] = expf(-(cs[j] + mmx));
  }
}

// ---------------------------------------------------------------------------
// Kernel 3a: K fragment-stream pack. KB [bh][s][d] -> KF chunks
// o = (wc*8 + ks)*64 + lane ; content[j] = K[t0+16*wc+l15][32*ks+8*lg+j].
// ---------------------------------------------------------------------------
__global__ __launch_bounds__(256) void k_kf(
    const unsigned short* __restrict__ kb, unsigned short* __restrict__ kfo)
{
  __shared__ unsigned short tile[64][264];
  const int bh = blockIdx.x, kt = blockIdx.y;
  const int t0 = kt*64;
  const int tid = threadIdx.x;

  #pragma unroll
  for (int i=0;i<8;i++){
    int f = tid + i*256;
    int r = f >> 5, c = (f & 31)*8;
    *(uint4*)&tile[r][c] = *(const uint4*)(kb + ((size_t)bh*SS + t0 + r)*DHH + c);
  }
  __syncthreads();

  unsigned short* dst = kfo + (size_t)(bh*32 + kt)*16384;
  #pragma unroll
  for (int i=0;i<8;i++){
    int o = tid + i*256;
    int lane = o & 63, g = o >> 6;
    int wcq = g >> 3, ks = g & 7;
    int l15 = lane & 15, lg = (lane >> 4) & 3;
    *(uint4*)(dst + (size_t)o*8) = *(const uint4*)&tile[16*wcq + l15][32*ks + 8*lg];
  }
}

// ---------------------------------------------------------------------------
// Kernel 3b: V fragment-stream pack.
// o = ((wc*8 + kst*4+nt)*64 + lane); content[j] = V[t0+32*kst+8*lg+j][64*wc+16*nt+l15].
// ---------------------------------------------------------------------------
__global__ __launch_bounds__(256) void k_vf(
    const unsigned short* __restrict__ vb, unsigned short* __restrict__ vfo)
{
  __shared__ unsigned short tile[64][264];
  const int bh = blockIdx.x, kt = blockIdx.y;
  const int t0 = kt*64;
  const int tid = threadIdx.x;

  #pragma unroll
  for (int i=0;i<8;i++){
    int f = tid + i*256;
    int r = f >> 5, c = (f & 31)*8;
    *(uint4*)&tile[r][c] = *(const uint4*)(vb + ((size_t)bh*SS + t0 + r)*DHH + c);
  }
  __syncthreads();

  unsigned short* dst = vfo + (size_t)(bh*32 + kt)*16384;
  #pragma unroll
  for (int i=0;i<8;i++){
    int o = tid + i*256;
    int lane = o & 63, g = o >> 6;
    int wc = g >> 3, fi = g & 7;
    int kst = fi >> 2, nt = fi & 3;
    int l15 = lane & 15, lg = (lane >> 4) & 3;
    unsigned short tmp[8];
    #pragma unroll
    for (int j=0;j<8;j++)
      tmp[j] = tile[32*kst + 8*lg + j][64*wc + 16*nt + l15];
    *(uint4*)(dst + (size_t)o*8) = *(uint4*)tmp;
  }
}

// ---------------------------------------------------------------------------
// Kernel 4: MFMA attention. 1024 blocks x 256 thr (4 waves), 16-row q-bands.
// Snake depth map: q=i>>5, j=i&31, rt = 127-32q-(q&1 ? 31-j : j) -> each CU's
// four co-resident depths sum ~const; deepest dispatched first.
// Per tile: kf stream -> QK(8 MFMA) -> W(2KB LDS) -> [lgkm0;bar] ->
// vf stream + W reads -> PV(8 MFMA) -> [lgkm0;bar]. No vmem at barriers.
// ---------------------------------------------------------------------------
__global__ __launch_bounds__(256) void k_attn(
    const unsigned short* __restrict__ qb, const unsigned short* __restrict__ kfr,
    const unsigned short* __restrict__ vfr,
    const float* __restrict__ ab, const float* __restrict__ mb,
    const float* __restrict__ flr, const float* __restrict__ ln_w,
    float* __restrict__ out)
{
  __shared__ __align__(16) char smW[16*128];   // 16 rows x 128B, swizzled
  __shared__ float smRed[16*4];
  __shared__ float smS1[16*4];
  __shared__ float smS2[16*4];

  const int bid = blockIdx.x;
  const int bh  = bid & 7;                 // XCD pin
  const int i   = bid >> 3;                // 0..127
  const int q   = i >> 5, j = i & 31;
  const int rt  = 127 - 32*q - ((q & 1) ? (31 - j) : j);
  const int s0  = rt * 16;
  const int nkt = (16*rt + 79) >> 6;       // 1..32

  const int tid  = threadIdx.x;
  const int lane = tid & 63;
  const int wc   = tid >> 6;               // wave 0..3
  const int l15  = lane & 15, lg = lane >> 4;
  const int bhoff = bh * SS;
  const int b = bh >> 2, h = bh & 3;
  const int trel = 16*wc + l15;

  const unsigned short* kfh = kfr + (size_t)bh*32*16384;
  const unsigned short* vfh = vfr + (size_t)bh*32*16384;

  // Q register-resident: 16 rows
  short8 qf[8];
  {
    const unsigned short* qp = qb + ((size_t)bh*SS + s0)*DHH;
    #pragma unroll
    for (int ks=0; ks<8; ++ks)
      qf[ks] = *(const short8*)(qp + l15*DHH + 32*ks + 8*lg);
  }
  float mrow[4];
  #pragma unroll
  for (int rr=0; rr<4; ++rr)
    mrow[rr] = mb[bhoff + s0 + 4*lg + rr];

  f32x4 oacc[4];
  #pragma unroll
  for (int nt=0; nt<4; ++nt)
    oacc[nt] = (f32x4){0.f,0.f,0.f,0.f};
  float denp[4] = {0.f,0.f,0.f,0.f};

  for (int kt = 0; kt < nkt; ++kt) {
    const int t0 = kt*64;

    // ---- QK: K fragment stream (8 x 1KB coalesced), 8 MFMA ----
    f32x4 sacc = (f32x4){0.f,0.f,0.f,0.f};
    const float avC = ab[bhoff + t0 + trel];
    {
      const unsigned short* kfp = kfh + (size_t)kt*16384 + (size_t)wc*4096 + lane*8;
      short8 k0 = *(const short8*)(kfp + 0*512);
      short8 k1 = *(const short8*)(kfp + 1*512);
      short8 k2 = *(const short8*)(kfp + 2*512);
      short8 k3 = *(const short8*)(kfp + 3*512);
      short8 k4 = *(const short8*)(kfp + 4*512);
      short8 k5 = *(const short8*)(kfp + 5*512);
      short8 k6 = *(const short8*)(kfp + 6*512);
      short8 k7 = *(const short8*)(kfp + 7*512);
      __builtin_amdgcn_s_setprio(1);
      sacc = __builtin_amdgcn_mfma_f32_16x16x32_bf16(qf[0], k0, sacc, 0,0,0);
      sacc = __builtin_amdgcn_mfma_f32_16x16x32_bf16(qf[1], k1, sacc, 0,0,0);
      sacc = __builtin_amdgcn_mfma_f32_16x16x32_bf16(qf[2], k2, sacc, 0,0,0);
      sacc = __builtin_amdgcn_mfma_f32_16x16x32_bf16(qf[3], k3, sacc, 0,0,0);
      sacc = __builtin_amdgcn_mfma_f32_16x16x32_bf16(qf[4], k4, sacc, 0,0,0);
      sacc = __builtin_amdgcn_mfma_f32_16x16x32_bf16(qf[5], k5, sacc, 0,0,0);
      sacc = __builtin_amdgcn_mfma_f32_16x16x32_bf16(qf[6], k6, sacc, 0,0,0);
      sacc = __builtin_amdgcn_mfma_f32_16x16x32_bf16(qf[7], k7, sacc, 0,0,0);
      __builtin_amdgcn_s_setprio(0);
    }

    // ---- W = mask * qk * exp(a[t]-m[s]) -> bf16 swizzled LDS ----
    {
      const bool lastt = (kt == nkt-1);
      #pragma unroll
      for (int rr=0; rr<4; ++rr) {
        const int rib = 4*lg + rr;           // 0..15
        float wv = sacc[rr] * __expf(avC - mrow[rr]);
        if (lastt && (t0 + trel > s0 + rib)) wv = 0.f;
        denp[rr] += wv;
        *(unsigned short*)(smW + (size_t)rib*128 + (((trel >> 3) ^ (rib & 7))<<4)
                            + ((trel & 7)<<1)) = f2b(wv);
      }
    }
    asm volatile("s_waitcnt lgkmcnt(0)" ::: "memory");
    __builtin_amdgcn_s_barrier();
    asm volatile("" ::: "memory");

    // ---- PV: V fragment stream + W from LDS, 8 MFMA ----
    {
      const unsigned short* vfp = vfh + (size_t)kt*16384 + (size_t)wc*4096 + lane*8;
      short8 v0 = *(const short8*)(vfp + 0*512);
      short8 v1 = *(const short8*)(vfp + 1*512);
      short8 v2 = *(const short8*)(vfp + 2*512);
      short8 v3 = *(const short8*)(vfp + 3*512);
      short8 v4 = *(const short8*)(vfp + 4*512);
      short8 v5 = *(const short8*)(vfp + 5*512);
      short8 v6 = *(const short8*)(vfp + 6*512);
      short8 v7 = *(const short8*)(vfp + 7*512);
      const int sr0 = l15;
      short8 w00 = *(const short8*)(smW + (size_t)sr0*128 + ((lg^(sr0&7))<<4));
      short8 w01 = *(const short8*)(smW + (size_t)sr0*128 + (((4+lg)^(sr0&7))<<4));
      __builtin_amdgcn_s_setprio(1);
      oacc[0] = __builtin_amdgcn_mfma_f32_16x16x32_bf16(w00, v0, oacc[0], 0,0,0);
      oacc[1] = __builtin_amdgcn_mfma_f32_16x16x32_bf16(w00, v1, oacc[1], 0,0,0);
      oacc[2] = __builtin_amdgcn_mfma_f32_16x16x32_bf16(w00, v2, oacc[2], 0,0,0);
      oacc[3] = __builtin_amdgcn_mfma_f32_16x16x32_bf16(w00, v3, oacc[3], 0,0,0);
      oacc[0] = __builtin_amdgcn_mfma_f32_16x16x32_bf16(w01, v4, oacc[0], 0,0,0);
      oacc[1] = __builtin_amdgcn_mfma_f32_16x16x32_bf16(w01, v5, oacc[1], 0,0,0);
      oacc[2] = __builtin_amdgcn_mfma_f32_16x16x32_bf16(w01, v6, oacc[2], 0,0,0);
      oacc[3] = __builtin_amdgcn_mfma_f32_16x16x32_bf16(w01, v7, oacc[3], 0,0,0);
      __builtin_amdgcn_s_setprio(0);
    }
    asm volatile("s_waitcnt lgkmcnt(0)" ::: "memory");
    __builtin_amdgcn_s_barrier();
    asm volatile("" ::: "memory");
  }

  // ---- epilogue: den reduce, normalizer, LN, write ----
  #pragma unroll
  for (int rr=0; rr<4; ++rr) {
    float v = denp[rr];
    v += __shfl_xor(v, 1); v += __shfl_xor(v, 2);
    v += __shfl_xor(v, 4); v += __shfl_xor(v, 8);
    if (l15 == 0) smRed[(4*lg + rr)*4 + wc] = v;
  }
  __syncthreads();

  float inv[4];
  #pragma unroll
  for (int rr=0; rr<4; ++rr) {
    const int rib = 4*lg + rr;
    float dsum = smRed[rib*4+0] + smRed[rib*4+1] + smRed[rib*4+2] + smRed[rib*4+3];
    float f = flr[bhoff + s0 + rib];
    inv[rr] = 1.f / (fmaxf(fabsf(dsum), f) + 1e-8f);
  }

  float s1p[4] = {0,0,0,0}, s2p[4] = {0,0,0,0};
  #pragma unroll
  for (int nt=0; nt<4; ++nt)
    #pragma unroll
    for (int rr=0; rr<4; ++rr) {
      float v = oacc[nt][rr] * inv[rr];
      oacc[nt][rr] = v;
      s1p[rr] += v;
      s2p[rr] += v*v;
    }
  #pragma unroll
  for (int rr=0; rr<4; ++rr) {
    float a = s1p[rr], qv = s2p[rr];
    a += __shfl_xor(a, 1); a += __shfl_xor(a, 2);
    a += __shfl_xor(a, 4); a += __shfl_xor(a, 8);
    qv += __shfl_xor(qv, 1); qv += __shfl_xor(qv, 2);
    qv += __shfl_xor(qv, 4); qv += __shfl_xor(qv, 8);
    if (l15 == 0) {
      const int rib = 4*lg + rr;
      smS1[rib*4 + wc] = a;
      smS2[rib*4 + wc] = qv;
    }
  }
  __syncthreads();

  float g4[4];
  #pragma unroll
  for (int nt=0; nt<4; ++nt) g4[nt] = 1.f + ln_w[h*DHH + 64*wc + 16*nt + l15];

  #pragma unroll
  for (int rr=0; rr<4; ++rr) {
    const int rib = 4*lg + rr;
    const float ms = smS1[rib*4+0] + smS1[rib*4+1] + smS1[rib*4+2] + smS1[rib*4+3];
    const float sq = smS2[rib*4+0] + smS2[rib*4+1] + smS2[rib*4+2] + smS2[rib*4+3];
    const float mean = ms * (1.f/DHH);
    const float var  = sq * (1.f/DHH) - mean*mean;
    const float rstd = rsqrtf(var + 1e-5f);
    float* op = out + ((size_t)(b*SS + s0 + rib))*DD + h*DHH;
    #pragma unroll
    for (int nt=0; nt<4; ++nt)
      op[64*wc + 16*nt + l15] = (oacc[nt][rr] - mean)*rstd*g4[nt];
  }
}

// ---------------------------------------------------------------------------
extern "C" void kernel_launch(void* const* d_in, const int* in_sizes, int n_in,
                              void* d_out, int out_size, void* d_ws, size_t ws_size,
                              hipStream_t stream) {
  (void)in_sizes; (void)n_in; (void)out_size; (void)ws_size;
  const float* x    = (const float*)d_in[0];
  const float* wq   = (const float*)d_in[1];
  const float* wk   = (const float*)d_in[2];
  const float* wv   = (const float*)d_in[3];
  const float* wi   = (const float*)d_in[4];
  const float* bi   = (const float*)d_in[5];
  const float* wf   = (const float*)d_in[6];
  const float* bf   = (const float*)d_in[7];
  const float* ln_w = (const float*)d_in[8];
  float* out = (float*)d_out;
  char* ws = (char*)d_ws;

  unsigned short* QB = (unsigned short*)(ws + QB_OFF);
  unsigned short* KB = (unsigned short*)(ws + KB_OFF);
  unsigned short* VF = (unsigned short*)(ws + VF_OFF);
  unsigned short* VB = (unsigned short*)(ws + VB_OFF);
  unsigned short* KF = (unsigned short*)(ws + KF_OFF);
  float* IG  = (float*)(ws + IG_OFF);
  float* LSF = (float*)(ws + LSF_OFF);
  float* AA  = (float*)(ws + AA_OFF);
  float* MM  = (float*)(ws + MM_OFF);
  float* FLR = (float*)(ws + FLR_OFF);
  float* WSI = (float*)(ws + WSI_OFF);
  float* WSF = (float*)(ws + WSF_OFF);

  k_gw<<<32, 256, 0, stream>>>(wi, wf, WSI, WSF);
  k_proj<<<1024, 256, 0, stream>>>(x, wq, wk, wv, WSI, bi, WSF, bf, QB, KB, VB, IG, LSF);
  k_scan<<<BHH, 256, 0, stream>>>(IG, LSF, AA, MM, FLR);
  k_kf<<<dim3(BHH, SS/64), 256, 0, stream>>>(KB, KF);
  k_vf<<<dim3(BHH, SS/64), 256, 0, stream>>>(VB, VF);
  k_attn<<<1024, 256, 0, stream>>>(QB, KF, VF, AA, MM, FLR, ln_w, out);
}